// Round 1
// baseline (497.734 us; speedup 1.0000x reference)
//
#include <hip/hip_runtime.h>
#include <math.h>

#define Bb 4
#define Hh 12
#define BH 48
#define Ss 4096
#define Dd 64
#define Mm 64
#define LSEG 64
#define NCH 8
#define CHUNK (Ss/NCH)          // 512
#define PPART (2*Mm + Mm*Dd)    // 4224 floats per partial
#define SCALE 0.125f
#define PST 68                  // padded stride for pinv LDS buffers (16B aligned rows, bank-spread)

// ---------------- K1: landmarks (segment means) ----------------
__global__ __launch_bounds__(64) void k_landmarks(const float* __restrict__ Q,
                                                  const float* __restrict__ Kg,
                                                  float* __restrict__ qlm,
                                                  float* __restrict__ klm) {
    int m = blockIdx.x, bh = blockIdx.y;
    int d = threadIdx.x;
    const float* src = blockIdx.z ? Kg : Q;
    float* dst = blockIdx.z ? klm : qlm;
    const float* base = src + ((size_t)bh * Ss + (size_t)m * LSEG) * Dd + d;
    float acc = 0.f;
#pragma unroll
    for (int l = 0; l < LSEG; l++) acc += base[(size_t)l * Dd];
    dst[(bh * Mm + m) * Dd + d] = acc * (1.0f / LSEG);
}

// ---------------- K2: landmark softmax matrix + init_coef reductions ----------------
__global__ __launch_bounds__(256) void k_lmsm(const float* __restrict__ qlm,
                                              const float* __restrict__ klm,
                                              float* __restrict__ smat,
                                              unsigned int* __restrict__ coef) {
    int bh = blockIdx.x, t = threadIdx.x;
    __shared__ float kl[Mm * Dd];         // broadcast-only reads -> no pad
    __shared__ float Lp[Mm][Mm + 1];
    const float* kb = klm + bh * Mm * Dd;
    for (int i = t; i < Mm * Dd; i += 256) kl[i] = kb[i];
    int n = t >> 2, c = t & 3;
    const float* qb = qlm + (bh * Mm + n) * Dd;
    float q[Dd];
#pragma unroll
    for (int d4 = 0; d4 < 16; d4++) {
        float4 v = *(const float4*)(qb + d4 * 4);
        q[d4 * 4 + 0] = v.x; q[d4 * 4 + 1] = v.y; q[d4 * 4 + 2] = v.z; q[d4 * 4 + 3] = v.w;
    }
    __syncthreads();
#pragma unroll
    for (int jj = 0; jj < 16; jj++) {
        int m = c * 16 + jj;
        const float4* krow = (const float4*)(kl + m * Dd);
        float s = 0.f;
#pragma unroll
        for (int d4 = 0; d4 < 16; d4++) {
            float4 kv = krow[d4];
            s += q[d4 * 4 + 0] * kv.x + q[d4 * 4 + 1] * kv.y
               + q[d4 * 4 + 2] * kv.z + q[d4 * 4 + 3] * kv.w;
        }
        Lp[n][m] = s * SCALE;
    }
    __syncthreads();
    float p[Mm]; float mx = -INFINITY;
#pragma unroll
    for (int m = 0; m < Mm; m++) { p[m] = Lp[n][m]; mx = fmaxf(mx, p[m]); }
    float den = 0.f;
#pragma unroll
    for (int m = 0; m < Mm; m++) { p[m] = expf(p[m] - mx); den += p[m]; }
    float inv = 1.0f / den;
    __syncthreads();   // all logit reads done before overwrite
#pragma unroll
    for (int jj = 0; jj < 16; jj++) {
        int m = c * 16 + jj;
        Lp[n][m] = p[m] * inv;
    }
    __syncthreads();
    float* sg = smat + bh * Mm * Mm;
    for (int i = t; i < Mm * Mm; i += 256) sg[i] = Lp[i >> 6][i & 63];
    if (t < Mm) {
        int m = t; float cs = 0.f;
#pragma unroll
        for (int nn = 0; nn < Mm; nn++) cs += Lp[nn][m];
        atomicMax(coef + 0, __float_as_uint(cs));     // max column-sum (axis=-2)
    } else if (t < 2 * Mm) {
        int nn = t - Mm; float rs = 0.f;
#pragma unroll
        for (int m = 0; m < Mm; m++) rs += Lp[nn][m];
        atomicMax(coef + 1, __float_as_uint(rs));     // max row-sum (axis=-1)
    }
}

// ---------------- K3: Newton-Schulz iterative pinv ----------------
// 4x4 register-blocked 64^3 LDS matmul; rows interleaved (i = ti + 16*ii) so
// float4 reads land 2-way bank-aliased (free). Dst = scl*(diag*I + sgn*(A@B)).
__device__ __forceinline__ void mm4x4(float* __restrict__ Dm,
                                      const float* __restrict__ Am,
                                      const float* __restrict__ Bm,
                                      int ti, int tj, float diag, float sgn, float scl) {
    float acc[4][4];
#pragma unroll
    for (int a = 0; a < 4; a++)
#pragma unroll
        for (int b = 0; b < 4; b++) acc[a][b] = 0.f;
#pragma unroll
    for (int k4 = 0; k4 < 16; k4++) {
        float aa[4][4], bb[4][4];
#pragma unroll
        for (int ii = 0; ii < 4; ii++) {
            float4 v = *(const float4*)(Am + (ti + 16 * ii) * PST + k4 * 4);
            aa[ii][0] = v.x; aa[ii][1] = v.y; aa[ii][2] = v.z; aa[ii][3] = v.w;
        }
#pragma unroll
        for (int kk = 0; kk < 4; kk++) {
            float4 v = *(const float4*)(Bm + (k4 * 4 + kk) * PST + tj * 4);
            bb[kk][0] = v.x; bb[kk][1] = v.y; bb[kk][2] = v.z; bb[kk][3] = v.w;
        }
#pragma unroll
        for (int ii = 0; ii < 4; ii++)
#pragma unroll
            for (int kk = 0; kk < 4; kk++)
#pragma unroll
                for (int jj = 0; jj < 4; jj++)
                    acc[ii][jj] += aa[ii][kk] * bb[kk][jj];
    }
    int j0 = tj * 4;
#pragma unroll
    for (int ii = 0; ii < 4; ii++) {
        int i = ti + 16 * ii;
        float4 r;
        r.x = scl * (((i == j0 + 0) ? diag : 0.f) + sgn * acc[ii][0]);
        r.y = scl * (((i == j0 + 1) ? diag : 0.f) + sgn * acc[ii][1]);
        r.z = scl * (((i == j0 + 2) ? diag : 0.f) + sgn * acc[ii][2]);
        r.w = scl * (((i == j0 + 3) ? diag : 0.f) + sgn * acc[ii][3]);
        *(float4*)(Dm + i * PST + j0) = r;
    }
}

__global__ __launch_bounds__(256) void k_pinv(const float* __restrict__ smat,
                                              const unsigned int* __restrict__ coef,
                                              float* __restrict__ atil) {
    extern __shared__ float lds[];
    float* Ab = lds;                 // source matrix
    float* B1 = Ab + Mm * PST;       // X ping
    float* B2 = B1 + Mm * PST;       // mo
    float* B3 = B2 + Mm * PST;       // term1/term3
    float* B4 = B3 + Mm * PST;       // term2 / X pong
    int bh = blockIdx.x, t = threadIdx.x;
    const float* ab = smat + bh * Mm * Mm;
    for (int i = t; i < Mm * Mm; i += 256) Ab[(i >> 6) * PST + (i & 63)] = ab[i];
    __syncthreads();
    float inv = 1.0f / (__uint_as_float(coef[0]) * __uint_as_float(coef[1]));
    for (int i = t; i < Mm * Mm; i += 256) {
        int r = i >> 6, c = i & 63;
        B1[r * PST + c] = Ab[c * PST + r] * inv;   // X0 = A^T / init_coef
    }
    __syncthreads();
    int ti = t >> 4, tj = t & 15;
    float* Xc = B1;
    for (int it = 0; it < 6; it++) {
        float* D = (Xc == B1) ? B4 : B1;
        mm4x4(B2, Ab, Xc, ti, tj, 0.f, 1.f, 1.f);     // mo = A @ X
        __syncthreads();
        for (int i = t; i < Mm * Mm; i += 256) {       // term1 = 7I - mo
            int r = i >> 6, c = i & 63;
            B3[r * PST + c] = ((r == c) ? 7.f : 0.f) - B2[r * PST + c];
        }
        __syncthreads();
        mm4x4(D, B2, B3, ti, tj, 15.f, -1.f, 1.f);     // term2 = 15I - mo@term1
        __syncthreads();
        mm4x4(B3, B2, D, ti, tj, 13.f, -1.f, 1.f);     // term3 = 13I - mo@term2
        __syncthreads();
        mm4x4(D, Xc, B3, ti, tj, 0.f, 1.f, 0.25f);     // Xnew = 0.25 * X@term3
        __syncthreads();
        Xc = D;
    }
    float* ob = atil + bh * Mm * Mm;
    for (int i = t; i < Mm * Mm; i += 256) ob[i] = Xc[(i >> 6) * PST + (i & 63)];
}

// ---------------- K4: B_tilde @ V partials (online softmax over s-chunks) ----------------
__global__ __launch_bounds__(256) void k_bvp(const float* __restrict__ qlm,
                                             const float* __restrict__ Kg,
                                             const float* __restrict__ Vg,
                                             float* __restrict__ part) {
    int ch = blockIdx.x, bh = blockIdx.y, t = threadIdx.x;
    __shared__ float Kt[64 * Dd];        // broadcast-ish reads -> no pad (aligned float4)
    __shared__ float Vt[64 * Dd];
    __shared__ float Lg[Mm][64 + 1];
    int m = t >> 2, c = t & 3, d0 = c * 16;
    const float* qb = qlm + (bh * Mm + m) * Dd;
    float q[Dd];
#pragma unroll
    for (int d4 = 0; d4 < 16; d4++) {
        float4 v = *(const float4*)(qb + d4 * 4);
        q[d4 * 4 + 0] = v.x; q[d4 * 4 + 1] = v.y; q[d4 * 4 + 2] = v.z; q[d4 * 4 + 3] = v.w;
    }
    float acc[16];
#pragma unroll
    for (int ii = 0; ii < 16; ii++) acc[ii] = 0.f;
    float rmax = -INFINITY, rden = 0.f;
    for (int tile = 0; tile < CHUNK / 64; tile++) {
        size_t base = ((size_t)bh * Ss + (size_t)ch * CHUNK + tile * 64) * Dd;
        const float4* kb4 = (const float4*)(Kg + base);
        const float4* vb4 = (const float4*)(Vg + base);
        __syncthreads();
        for (int i4 = t; i4 < 64 * 16; i4 += 256) {
            float4 kv = kb4[i4], vv = vb4[i4];
            ((float4*)Kt)[i4] = kv;
            ((float4*)Vt)[i4] = vv;
        }
        __syncthreads();
#pragma unroll
        for (int jj = 0; jj < 16; jj++) {
            int j = c * 16 + jj;
            const float4* krow = (const float4*)(Kt + j * Dd);
            float s = 0.f;
#pragma unroll
            for (int d4 = 0; d4 < 16; d4++) {
                float4 kv = krow[d4];
                s += q[d4 * 4 + 0] * kv.x + q[d4 * 4 + 1] * kv.y
                   + q[d4 * 4 + 2] * kv.z + q[d4 * 4 + 3] * kv.w;
            }
            Lg[m][j] = s * SCALE;
        }
        __syncthreads();
        float tm = -INFINITY;
#pragma unroll
        for (int j = 0; j < 64; j++) tm = fmaxf(tm, Lg[m][j]);
        float nm = fmaxf(rmax, tm);
        float rf = expf(rmax - nm);   // rmax=-inf first iter -> rf=0, nm finite
        rden *= rf;
#pragma unroll
        for (int ii = 0; ii < 16; ii++) acc[ii] *= rf;
#pragma unroll
        for (int j = 0; j < 64; j++) {
            float w = expf(Lg[m][j] - nm);
            rden += w;
            const float4* vrow = (const float4*)(Vt + j * Dd + d0);
            float4 v0 = vrow[0], v1 = vrow[1], v2 = vrow[2], v3 = vrow[3];
            acc[0]  += w * v0.x; acc[1]  += w * v0.y; acc[2]  += w * v0.z; acc[3]  += w * v0.w;
            acc[4]  += w * v1.x; acc[5]  += w * v1.y; acc[6]  += w * v1.z; acc[7]  += w * v1.w;
            acc[8]  += w * v2.x; acc[9]  += w * v2.y; acc[10] += w * v2.z; acc[11] += w * v2.w;
            acc[12] += w * v3.x; acc[13] += w * v3.y; acc[14] += w * v3.z; acc[15] += w * v3.w;
        }
        rmax = nm;
    }
    float* p = part + ((size_t)bh * NCH + ch) * PPART;
    if (c == 0) { p[m] = rmax; p[Mm + m] = rden; }
    float4* pa4 = (float4*)(p + 2 * Mm + m * Dd + d0);
    pa4[0] = make_float4(acc[0],  acc[1],  acc[2],  acc[3]);
    pa4[1] = make_float4(acc[4],  acc[5],  acc[6],  acc[7]);
    pa4[2] = make_float4(acc[8],  acc[9],  acc[10], acc[11]);
    pa4[3] = make_float4(acc[12], acc[13], acc[14], acc[15]);
}

// ---------------- K5: combine partials -> bv, then abv = A_tilde @ bv ----------------
__global__ __launch_bounds__(256) void k_bvc(const float* __restrict__ part,
                                             const float* __restrict__ atil,
                                             float* __restrict__ abv) {
    int bh = blockIdx.x, t = threadIdx.x;
    __shared__ float bvs[Mm][Dd + 1];
    __shared__ float Ams[Mm * (Mm + 1)];
    const float* ab = atil + bh * Mm * Mm;
    for (int i = t; i < Mm * Mm; i += 256) Ams[(i >> 6) * (Mm + 1) + (i & 63)] = ab[i];
    int m = t >> 2, c = t & 3, d0 = c * 16;
    const float* pb = part + (size_t)bh * NCH * PPART;
    float pms[NCH]; float gm = -INFINITY;
#pragma unroll
    for (int ch = 0; ch < NCH; ch++) { pms[ch] = pb[ch * PPART + m]; gm = fmaxf(gm, pms[ch]); }
    float den = 0.f; float acc[16];
#pragma unroll
    for (int ii = 0; ii < 16; ii++) acc[ii] = 0.f;
#pragma unroll
    for (int ch = 0; ch < NCH; ch++) {
        float f = expf(pms[ch] - gm);
        den += f * pb[ch * PPART + Mm + m];
        const float4* pa = (const float4*)(pb + ch * PPART + 2 * Mm + m * Dd + d0);
        float4 a0 = pa[0], a1 = pa[1], a2 = pa[2], a3 = pa[3];
        acc[0]  += f * a0.x; acc[1]  += f * a0.y; acc[2]  += f * a0.z; acc[3]  += f * a0.w;
        acc[4]  += f * a1.x; acc[5]  += f * a1.y; acc[6]  += f * a1.z; acc[7]  += f * a1.w;
        acc[8]  += f * a2.x; acc[9]  += f * a2.y; acc[10] += f * a2.z; acc[11] += f * a2.w;
        acc[12] += f * a3.x; acc[13] += f * a3.y; acc[14] += f * a3.z; acc[15] += f * a3.w;
    }
    float inv = 1.0f / den;
#pragma unroll
    for (int ii = 0; ii < 16; ii++) bvs[m][d0 + ii] = acc[ii] * inv;
    __syncthreads();
    int j = t & 63, i0 = (t >> 6) << 4;
    float outv[16];
#pragma unroll
    for (int ii = 0; ii < 16; ii++) outv[ii] = 0.f;
#pragma unroll
    for (int k = 0; k < Mm; k++) {
        float bk = bvs[k][j];
#pragma unroll
        for (int ii = 0; ii < 16; ii++) outv[ii] += Ams[(i0 + ii) * (Mm + 1) + k] * bk;
    }
    float* ob = abv + bh * Mm * Dd;
#pragma unroll
    for (int ii = 0; ii < 16; ii++) ob[(i0 + ii) * Dd + j] = outv[ii];
}

// ---------------- K6: F_tilde softmax fused with F_tilde @ abv ----------------
__global__ __launch_bounds__(256) void k_fout(const float* __restrict__ Qg,
                                              const float* __restrict__ klm,
                                              const float* __restrict__ abvg,
                                              float* __restrict__ Og) {
    int st = blockIdx.x, bh = blockIdx.y, t = threadIdx.x;
    __shared__ float kl[Mm * Dd];
    __shared__ float abs_[Mm * Dd];
    __shared__ float Lp[64][Mm + 1];
    const float* kb = klm + bh * Mm * Dd;
    const float* abb = abvg + bh * Mm * Dd;
    for (int i = t; i < Mm * Dd; i += 256) { kl[i] = kb[i]; abs_[i] = abb[i]; }
    int r = t >> 2, c = t & 3;
    const float* qb = Qg + ((size_t)bh * Ss + (size_t)st * 64 + r) * Dd;
    float q[Dd];
#pragma unroll
    for (int d4 = 0; d4 < 16; d4++) {
        float4 v = *(const float4*)(qb + d4 * 4);
        q[d4 * 4 + 0] = v.x; q[d4 * 4 + 1] = v.y; q[d4 * 4 + 2] = v.z; q[d4 * 4 + 3] = v.w;
    }
    __syncthreads();
#pragma unroll
    for (int jj = 0; jj < 16; jj++) {
        int m = c * 16 + jj;
        const float4* krow = (const float4*)(kl + m * Dd);
        float s = 0.f;
#pragma unroll
        for (int d4 = 0; d4 < 16; d4++) {
            float4 kv = krow[d4];
            s += q[d4 * 4 + 0] * kv.x + q[d4 * 4 + 1] * kv.y
               + q[d4 * 4 + 2] * kv.z + q[d4 * 4 + 3] * kv.w;
        }
        Lp[r][m] = s * SCALE;
    }
    __syncthreads();
    float p[Mm]; float mx = -INFINITY;
#pragma unroll
    for (int m = 0; m < Mm; m++) { p[m] = Lp[r][m]; mx = fmaxf(mx, p[m]); }
    float den = 0.f;
#pragma unroll
    for (int m = 0; m < Mm; m++) { p[m] = expf(p[m] - mx); den += p[m]; }
    float inv = 1.0f / den;
    float o[16];
#pragma unroll
    for (int ii = 0; ii < 16; ii++) o[ii] = 0.f;
#pragma unroll
    for (int m = 0; m < Mm; m++) {
        float pm = p[m];
        const float4* arow = (const float4*)(abs_ + m * Dd + c * 16);
        float4 a0 = arow[0], a1 = arow[1], a2 = arow[2], a3 = arow[3];
        o[0]  += pm * a0.x; o[1]  += pm * a0.y; o[2]  += pm * a0.z; o[3]  += pm * a0.w;
        o[4]  += pm * a1.x; o[5]  += pm * a1.y; o[6]  += pm * a1.z; o[7]  += pm * a1.w;
        o[8]  += pm * a2.x; o[9]  += pm * a2.y; o[10] += pm * a2.z; o[11] += pm * a2.w;
        o[12] += pm * a3.x; o[13] += pm * a3.y; o[14] += pm * a3.z; o[15] += pm * a3.w;
    }
    __syncthreads();   // all Lp reads done
#pragma unroll
    for (int ii = 0; ii < 16; ii++) Lp[r][c * 16 + ii] = o[ii] * inv;
    __syncthreads();
    float4* ob = (float4*)(Og + ((size_t)bh * Ss + (size_t)st * 64) * Dd);
    for (int k = 0; k < 4; k++) {
        int i4 = t + k * 256;
        int row = i4 >> 4, col = (i4 & 15) * 4;
        float4 v;
        v.x = Lp[row][col + 0]; v.y = Lp[row][col + 1];
        v.z = Lp[row][col + 2]; v.w = Lp[row][col + 3];
        ob[i4] = v;
    }
}

extern "C" void kernel_launch(void* const* d_in, const int* in_sizes, int n_in,
                              void* d_out, int out_size, void* d_ws, size_t ws_size,
                              hipStream_t stream) {
    const float* Q = (const float*)d_in[0];
    const float* K = (const float*)d_in[1];
    const float* V = (const float*)d_in[2];
    float* out = (float*)d_out;
    float* ws = (float*)d_ws;
    unsigned int* coef = (unsigned int*)d_ws;
    float* qlm  = ws + 16;
    float* klm  = qlm  + BH * Mm * Dd;
    float* smat = klm  + BH * Mm * Dd;
    float* atil = smat + BH * Mm * Mm;
    float* abv  = atil + BH * Mm * Mm;
    float* part = abv  + BH * Mm * Dd;

    hipMemsetAsync(d_ws, 0, 64, stream);   // init coef maxes to 0 (all maxed values positive)

    k_landmarks<<<dim3(Mm, BH, 2), dim3(64), 0, stream>>>(Q, K, qlm, klm);
    k_lmsm<<<dim3(BH), dim3(256), 0, stream>>>(qlm, klm, smat, coef);
    k_pinv<<<dim3(BH), dim3(256), 5 * Mm * PST * 4, stream>>>(smat, coef, atil);
    k_bvp<<<dim3(NCH, BH), dim3(256), 0, stream>>>(qlm, K, V, part);
    k_bvc<<<dim3(BH), dim3(256), 0, stream>>>(part, atil, abv);
    k_fout<<<dim3(Ss / 64, BH), dim3(256), 0, stream>>>(Q, klm, abv, out);
}

// Round 2
// 278.395 us; speedup vs baseline: 1.7879x; 1.7879x over previous
//
#include <hip/hip_runtime.h>
#include <math.h>

#define BH 48
#define Ss 4096
#define Dd 64
#define Mm 64
#define NCH 16
#define SCALE 0.125f
#define PST 68

typedef unsigned int u32;
typedef unsigned short u16;
typedef __attribute__((ext_vector_type(8))) short short8;
typedef __attribute__((ext_vector_type(4))) float floatx4;

union FRAG { uint4 u; short8 s; };

#define MFMA(a,b,c) __builtin_amdgcn_mfma_f32_16x16x32_bf16(a,b,c,0,0,0)

__device__ __forceinline__ u32 pack2_hi(float a, float b) {
    return (__float_as_uint(a) >> 16) | (__float_as_uint(b) & 0xFFFF0000u);
}
__device__ __forceinline__ float trunc_bf(float a) {
    return __uint_as_float(__float_as_uint(a) & 0xFFFF0000u);
}
__device__ __forceinline__ void split1(float v, u16& h, u16& l) {
    u32 u = __float_as_uint(v);
    h = (u16)(u >> 16);
    float r = v - __uint_as_float(u & 0xFFFF0000u);
    l = (u16)(__float_as_uint(r) >> 16);
}
__device__ __forceinline__ void split8(const float* v, short8& h, short8& l) {
    FRAG H, L;
    float r[8];
#pragma unroll
    for (int i = 0; i < 8; i++) r[i] = v[i] - trunc_bf(v[i]);
    H.u.x = pack2_hi(v[0], v[1]); H.u.y = pack2_hi(v[2], v[3]);
    H.u.z = pack2_hi(v[4], v[5]); H.u.w = pack2_hi(v[6], v[7]);
    L.u.x = pack2_hi(r[0], r[1]); L.u.y = pack2_hi(r[2], r[3]);
    L.u.z = pack2_hi(r[4], r[5]); L.u.w = pack2_hi(r[6], r[7]);
    h = H.s; l = L.s;
}
// XOR swizzle for [rows][64] bf16 LDS planes: keeps 8-elem chunks contiguous,
// spreads same-column b128 reads of different rows across bank quads.
__device__ __forceinline__ int swz(int row, int col) {
    return row * 64 + ((((col >> 3) ^ (row & 7)) << 3) | (col & 7));
}

// ---------------- K1: landmarks (segment means) + bf16 hi/lo copies ----------------
__global__ __launch_bounds__(64) void k_landmarks(const float* __restrict__ Q,
                                                  const float* __restrict__ Kg,
                                                  float* __restrict__ qlm,
                                                  float* __restrict__ klm,
                                                  u16* __restrict__ qlmh, u16* __restrict__ qlml,
                                                  u16* __restrict__ klmh, u16* __restrict__ klml) {
    int m = blockIdx.x, bh = blockIdx.y;
    int d = threadIdx.x;
    const float* src = blockIdx.z ? Kg : Q;
    float* dst = blockIdx.z ? klm : qlm;
    u16* dh = blockIdx.z ? klmh : qlmh;
    u16* dl = blockIdx.z ? klml : qlml;
    const float* base = src + ((size_t)bh * Ss + (size_t)m * 64) * Dd + d;
    float acc = 0.f;
#pragma unroll
    for (int l = 0; l < 64; l++) acc += base[(size_t)l * Dd];
    float v = acc * (1.0f / 64.0f);
    int idx = (bh * Mm + m) * Dd + d;
    dst[idx] = v;
    u16 h, lo; split1(v, h, lo);
    dh[idx] = h; dl[idx] = lo;
}

// ---------------- K2: landmark softmax matrix + init_coef reductions (fp32, unchanged) ----------------
__global__ __launch_bounds__(256) void k_lmsm(const float* __restrict__ qlm,
                                              const float* __restrict__ klm,
                                              float* __restrict__ smat,
                                              unsigned int* __restrict__ coef) {
    int bh = blockIdx.x, t = threadIdx.x;
    __shared__ float kl[Mm * Dd];
    __shared__ float Lp[Mm][Mm + 1];
    const float* kb = klm + bh * Mm * Dd;
    for (int i = t; i < Mm * Dd; i += 256) kl[i] = kb[i];
    int n = t >> 2, c = t & 3;
    const float* qb = qlm + (bh * Mm + n) * Dd;
    float q[Dd];
#pragma unroll
    for (int d4 = 0; d4 < 16; d4++) {
        float4 v = *(const float4*)(qb + d4 * 4);
        q[d4 * 4 + 0] = v.x; q[d4 * 4 + 1] = v.y; q[d4 * 4 + 2] = v.z; q[d4 * 4 + 3] = v.w;
    }
    __syncthreads();
#pragma unroll
    for (int jj = 0; jj < 16; jj++) {
        int m = c * 16 + jj;
        const float4* krow = (const float4*)(kl + m * Dd);
        float s = 0.f;
#pragma unroll
        for (int d4 = 0; d4 < 16; d4++) {
            float4 kv = krow[d4];
            s += q[d4 * 4 + 0] * kv.x + q[d4 * 4 + 1] * kv.y
               + q[d4 * 4 + 2] * kv.z + q[d4 * 4 + 3] * kv.w;
        }
        Lp[n][m] = s * SCALE;
    }
    __syncthreads();
    float p[Mm]; float mx = -INFINITY;
#pragma unroll
    for (int m = 0; m < Mm; m++) { p[m] = Lp[n][m]; mx = fmaxf(mx, p[m]); }
    float den = 0.f;
#pragma unroll
    for (int m = 0; m < Mm; m++) { p[m] = expf(p[m] - mx); den += p[m]; }
    float inv = 1.0f / den;
    __syncthreads();
#pragma unroll
    for (int jj = 0; jj < 16; jj++) {
        int m = c * 16 + jj;
        Lp[n][m] = p[m] * inv;
    }
    __syncthreads();
    float* sg = smat + bh * Mm * Mm;
    for (int i = t; i < Mm * Mm; i += 256) sg[i] = Lp[i >> 6][i & 63];
    if (t < Mm) {
        int m = t; float cs = 0.f;
#pragma unroll
        for (int nn = 0; nn < Mm; nn++) cs += Lp[nn][m];
        atomicMax(coef + 0, __float_as_uint(cs));
    } else if (t < 2 * Mm) {
        int nn = t - Mm; float rs = 0.f;
#pragma unroll
        for (int m = 0; m < Mm; m++) rs += Lp[nn][m];
        atomicMax(coef + 1, __float_as_uint(rs));
    }
}

// ---------------- K3: Newton-Schulz iterative pinv (fp32, unchanged) ----------------
__device__ __forceinline__ void mm4x4(float* __restrict__ Dm,
                                      const float* __restrict__ Am,
                                      const float* __restrict__ Bm,
                                      int ti, int tj, float diag, float sgn, float scl) {
    float acc[4][4];
#pragma unroll
    for (int a = 0; a < 4; a++)
#pragma unroll
        for (int b = 0; b < 4; b++) acc[a][b] = 0.f;
#pragma unroll
    for (int k4 = 0; k4 < 16; k4++) {
        float aa[4][4], bb[4][4];
#pragma unroll
        for (int ii = 0; ii < 4; ii++) {
            float4 v = *(const float4*)(Am + (ti + 16 * ii) * PST + k4 * 4);
            aa[ii][0] = v.x; aa[ii][1] = v.y; aa[ii][2] = v.z; aa[ii][3] = v.w;
        }
#pragma unroll
        for (int kk = 0; kk < 4; kk++) {
            float4 v = *(const float4*)(Bm + (k4 * 4 + kk) * PST + tj * 4);
            bb[kk][0] = v.x; bb[kk][1] = v.y; bb[kk][2] = v.z; bb[kk][3] = v.w;
        }
#pragma unroll
        for (int ii = 0; ii < 4; ii++)
#pragma unroll
            for (int kk = 0; kk < 4; kk++)
#pragma unroll
                for (int jj = 0; jj < 4; jj++)
                    acc[ii][jj] += aa[ii][kk] * bb[kk][jj];
    }
    int j0 = tj * 4;
#pragma unroll
    for (int ii = 0; ii < 4; ii++) {
        int i = ti + 16 * ii;
        float4 r;
        r.x = scl * (((i == j0 + 0) ? diag : 0.f) + sgn * acc[ii][0]);
        r.y = scl * (((i == j0 + 1) ? diag : 0.f) + sgn * acc[ii][1]);
        r.z = scl * (((i == j0 + 2) ? diag : 0.f) + sgn * acc[ii][2]);
        r.w = scl * (((i == j0 + 3) ? diag : 0.f) + sgn * acc[ii][3]);
        *(float4*)(Dm + i * PST + j0) = r;
    }
}

__global__ __launch_bounds__(256) void k_pinv(const float* __restrict__ smat,
                                              const unsigned int* __restrict__ coef,
                                              float* __restrict__ atil) {
    extern __shared__ float lds[];
    float* Ab = lds;
    float* B1 = Ab + Mm * PST;
    float* B2 = B1 + Mm * PST;
    float* B3 = B2 + Mm * PST;
    float* B4 = B3 + Mm * PST;
    int bh = blockIdx.x, t = threadIdx.x;
    const float* ab = smat + bh * Mm * Mm;
    for (int i = t; i < Mm * Mm; i += 256) Ab[(i >> 6) * PST + (i & 63)] = ab[i];
    __syncthreads();
    float inv = 1.0f / (__uint_as_float(coef[0]) * __uint_as_float(coef[1]));
    for (int i = t; i < Mm * Mm; i += 256) {
        int r = i >> 6, c = i & 63;
        B1[r * PST + c] = Ab[c * PST + r] * inv;
    }
    __syncthreads();
    int ti = t >> 4, tj = t & 15;
    float* Xc = B1;
    for (int it = 0; it < 6; it++) {
        float* D = (Xc == B1) ? B4 : B1;
        mm4x4(B2, Ab, Xc, ti, tj, 0.f, 1.f, 1.f);
        __syncthreads();
        for (int i = t; i < Mm * Mm; i += 256) {
            int r = i >> 6, c = i & 63;
            B3[r * PST + c] = ((r == c) ? 7.f : 0.f) - B2[r * PST + c];
        }
        __syncthreads();
        mm4x4(D, B2, B3, ti, tj, 15.f, -1.f, 1.f);
        __syncthreads();
        mm4x4(B3, B2, D, ti, tj, 13.f, -1.f, 1.f);
        __syncthreads();
        mm4x4(D, Xc, B3, ti, tj, 0.f, 1.f, 0.25f);
        __syncthreads();
        Xc = D;
    }
    float* ob = atil + bh * Mm * Mm;
    for (int i = t; i < Mm * Mm; i += 256) ob[i] = Xc[(i >> 6) * PST + (i & 63)];
}

// ---------------- K4: B_tilde @ V partials via MFMA (no max-sub; sum-combinable) ----------------
__global__ __launch_bounds__(256) void k_bvp(const float* __restrict__ Kg,
                                             const float* __restrict__ Vg,
                                             const u16* __restrict__ qlmh,
                                             const u16* __restrict__ qlml,
                                             float* __restrict__ pnum,
                                             float* __restrict__ pden) {
    __shared__ __align__(16) u16 Pb[2][4096];     // P split planes [m 64][s 64] swizzled
    __shared__ __align__(16) u16 vt[2][4096];     // V^T split planes [d 64][s 64] swizzled
    __shared__ __align__(16) float tmp[64 * 68];  // V staging f32
    int ch = blockIdx.x, bh = blockIdx.y;
    int t = threadIdx.x, w = t >> 6, l = t & 63, c = l & 15, hi = l >> 4;
    const float* Kbh = Kg + (size_t)bh * Ss * Dd;
    const float* Vbh = Vg + (size_t)bh * Ss * Dd;
    const u16* qh = qlmh + bh * Mm * Dd;
    const u16* ql = qlml + bh * Mm * Dd;
    floatx4 pvC[4];
    float denacc[16];
#pragma unroll
    for (int i = 0; i < 4; i++) pvC[i] = (floatx4){0.f, 0.f, 0.f, 0.f};
#pragma unroll
    for (int i = 0; i < 16; i++) denacc[i] = 0.f;

    for (int tile = 0; tile < 4; ++tile) {
        int s0 = ch * 256 + tile * 64;
        __syncthreads();   // prev PV done reading Pb/vt; tmp free
        // phase A: V tile -> tmp (coalesced)
        {
            int sl = t >> 2, q = (t & 3) * 16;
            const float4* vp = (const float4*)(Vbh + (size_t)(s0 + sl) * Dd + q);
            float4* dp = (float4*)(tmp + sl * 68 + q);
#pragma unroll
            for (int qq = 0; qq < 4; qq++) dp[qq] = vp[qq];
        }
        // QK^T: load K fragment (in-register convert), MFMA, exp, den, write P
        {
            int srow = s0 + w * 16 + c;
            const float* kp = Kbh + (size_t)srow * Dd + hi * 8;
            short8 kbh[2], kbl[2];
#pragma unroll
            for (int ks = 0; ks < 2; ks++) {
                float kv[8];
                float4 a = *(const float4*)(kp + ks * 32);
                float4 b = *(const float4*)(kp + ks * 32 + 4);
                kv[0] = a.x; kv[1] = a.y; kv[2] = a.z; kv[3] = a.w;
                kv[4] = b.x; kv[5] = b.y; kv[6] = b.z; kv[7] = b.w;
                split8(kv, kbh[ks], kbl[ks]);
            }
            floatx4 qkC[4];
#pragma unroll
            for (int i = 0; i < 4; i++) qkC[i] = (floatx4){0.f, 0.f, 0.f, 0.f};
#pragma unroll
            for (int mt = 0; mt < 4; mt++) {
#pragma unroll
                for (int ks = 0; ks < 2; ks++) {
                    short8 aH = *(const short8*)&qh[(mt * 16 + c) * 64 + ks * 32 + hi * 8];
                    short8 aL = *(const short8*)&ql[(mt * 16 + c) * 64 + ks * 32 + hi * 8];
                    qkC[mt] = MFMA(aH, kbh[ks], qkC[mt]);
                    qkC[mt] = MFMA(aL, kbh[ks], qkC[mt]);
                    qkC[mt] = MFMA(aH, kbl[ks], qkC[mt]);
                }
            }
#pragma unroll
            for (int mt = 0; mt < 4; mt++) {
#pragma unroll
                for (int r = 0; r < 4; r++) {
                    float pv = __expf(qkC[mt][r] * SCALE);
                    denacc[mt * 4 + r] += pv;
                    int m = mt * 16 + hi * 4 + r;
                    u16 h, lo; split1(pv, h, lo);
                    Pb[0][swz(m, w * 16 + c)] = h;
                    Pb[1][swz(m, w * 16 + c)] = lo;
                }
            }
        }
        __syncthreads();   // tmp ready, P writes done
        // phase B: tmp -> vt (transpose + split)
        {
            int d = t >> 2, sg = t & 3;
            float v[16];
#pragma unroll
            for (int j = 0; j < 16; j++) v[j] = tmp[(sg * 16 + j) * 68 + d];
            short8 h0, l0, h1, l1;
            split8(v, h0, l0); split8(v + 8, h1, l1);
            *(short8*)&vt[0][swz(d, sg * 16)] = h0;
            *(short8*)&vt[0][swz(d, sg * 16 + 8)] = h1;
            *(short8*)&vt[1][swz(d, sg * 16)] = l0;
            *(short8*)&vt[1][swz(d, sg * 16 + 8)] = l1;
        }
        __syncthreads();   // vt ready
        // PV: wave w owns m-tile w
#pragma unroll
        for (int ks = 0; ks < 2; ks++) {
            short8 pah = *(const short8*)&Pb[0][swz(w * 16 + c, ks * 32 + hi * 8)];
            short8 pal = *(const short8*)&Pb[1][swz(w * 16 + c, ks * 32 + hi * 8)];
#pragma unroll
            for (int dt = 0; dt < 4; dt++) {
                short8 vh = *(const short8*)&vt[0][swz(dt * 16 + c, ks * 32 + hi * 8)];
                short8 vl = *(const short8*)&vt[1][swz(dt * 16 + c, ks * 32 + hi * 8)];
                pvC[dt] = MFMA(pah, vh, pvC[dt]);
                pvC[dt] = MFMA(pal, vh, pvC[dt]);
                pvC[dt] = MFMA(pah, vl, pvC[dt]);
            }
        }
    }
    // write num partial [m 64][d 64]
    float* nb = pnum + (size_t)(bh * NCH + ch) * 4096;
#pragma unroll
    for (int dt = 0; dt < 4; dt++)
#pragma unroll
        for (int r = 0; r < 4; r++)
            nb[(w * 16 + hi * 4 + r) * 64 + dt * 16 + c] = pvC[dt][r];
    // reduce den over the 16 s-columns held across lanes (same hi group)
#pragma unroll
    for (int i = 0; i < 16; i++) {
        float v = denacc[i];
        v += __shfl_xor(v, 1); v += __shfl_xor(v, 2);
        v += __shfl_xor(v, 4); v += __shfl_xor(v, 8);
        denacc[i] = v;
    }
    if (c == 0) {
        float* db = pden + (size_t)((bh * NCH + ch) * 4 + w) * 64;
#pragma unroll
        for (int mt = 0; mt < 4; mt++)
#pragma unroll
            for (int r = 0; r < 4; r++)
                db[mt * 16 + hi * 4 + r] = denacc[mt * 4 + r];
    }
}

// ---------------- K5: combine partials -> bv, abv = A_tilde @ bv, emit abv^T split bf16 ----------------
__global__ __launch_bounds__(256) void k_bvc(const float* __restrict__ pnum,
                                             const float* __restrict__ pden,
                                             const float* __restrict__ atil,
                                             u16* __restrict__ abvh,
                                             u16* __restrict__ abvl) {
    int bh = blockIdx.x, t = threadIdx.x;
    __shared__ float bvs[Mm][Dd + 1];
    __shared__ float Ams[Mm * (Mm + 1)];
    const float* ab = atil + bh * Mm * Mm;
    for (int i = t; i < Mm * Mm; i += 256) Ams[(i >> 6) * 65 + (i & 63)] = ab[i];
    int m = t >> 2, c = t & 3, d0 = c * 16;
    float den = 0.f;
    const float* db = pden + (size_t)bh * NCH * 4 * 64;
#pragma unroll
    for (int i = 0; i < NCH * 4; i++) den += db[i * 64 + m];
    float acc[16];
#pragma unroll
    for (int i = 0; i < 16; i++) acc[i] = 0.f;
    const float* nb = pnum + (size_t)bh * NCH * 4096;
    for (int ch = 0; ch < NCH; ch++) {
        const float4* pa = (const float4*)(nb + ch * 4096 + m * 64 + d0);
#pragma unroll
        for (int q = 0; q < 4; q++) {
            float4 v = pa[q];
            acc[q * 4 + 0] += v.x; acc[q * 4 + 1] += v.y;
            acc[q * 4 + 2] += v.z; acc[q * 4 + 3] += v.w;
        }
    }
    float inv = 1.0f / den;
#pragma unroll
    for (int ii = 0; ii < 16; ii++) bvs[m][d0 + ii] = acc[ii] * inv;
    __syncthreads();
    int j = t & 63, i0 = (t >> 6) << 4;
    float outv[16];
#pragma unroll
    for (int ii = 0; ii < 16; ii++) outv[ii] = 0.f;
#pragma unroll
    for (int k = 0; k < Mm; k++) {
        float bk = bvs[k][j];
#pragma unroll
        for (int ii = 0; ii < 16; ii++) outv[ii] += Ams[(i0 + ii) * 65 + k] * bk;
    }
    u16* oh = abvh + bh * 4096;
    u16* ol = abvl + bh * 4096;
#pragma unroll
    for (int ii = 0; ii < 16; ii++) {
        u16 h, lo; split1(outv[ii], h, lo);
        oh[j * 64 + i0 + ii] = h;    // abv^T layout [d][m]
        ol[j * 64 + i0 + ii] = lo;
    }
}

// ---------------- K6: F_tilde softmax fused with F_tilde @ abv via MFMA ----------------
__global__ __launch_bounds__(256) void k_fout(const float* __restrict__ Qg,
                                              const u16* __restrict__ klmh,
                                              const u16* __restrict__ klml,
                                              const u16* __restrict__ abvh,
                                              const u16* __restrict__ abvl,
                                              float* __restrict__ Og) {
    __shared__ __align__(16) u16 Pw[4][2][1024];   // per-wave P split planes [s 16][m 64]
    int st = blockIdx.x, bh = blockIdx.y;
    int t = threadIdx.x, w = t >> 6, l = t & 63, c = l & 15, hi = l >> 4;
    int srow = st * 64 + w * 16 + c;
    // Q A-fragments (in-register convert)
    short8 qah[2], qal[2];
    {
        const float* qp = Qg + ((size_t)bh * Ss + srow) * Dd + hi * 8;
#pragma unroll
        for (int ks = 0; ks < 2; ks++) {
            float qv[8];
            float4 a = *(const float4*)(qp + ks * 32);
            float4 b = *(const float4*)(qp + ks * 32 + 4);
            qv[0] = a.x; qv[1] = a.y; qv[2] = a.z; qv[3] = a.w;
            qv[4] = b.x; qv[5] = b.y; qv[6] = b.z; qv[7] = b.w;
            split8(qv, qah[ks], qal[ks]);
        }
    }
    const u16* kh = klmh + bh * 4096;
    const u16* kl_ = klml + bh * 4096;
    floatx4 qkC[4];
#pragma unroll
    for (int i = 0; i < 4; i++) qkC[i] = (floatx4){0.f, 0.f, 0.f, 0.f};
#pragma unroll
    for (int mt = 0; mt < 4; mt++) {
#pragma unroll
        for (int ks = 0; ks < 2; ks++) {
            short8 bH = *(const short8*)&kh[(mt * 16 + c) * 64 + ks * 32 + hi * 8];
            short8 bL = *(const short8*)&kl_[(mt * 16 + c) * 64 + ks * 32 + hi * 8];
            qkC[mt] = MFMA(qah[ks], bH, qkC[mt]);
            qkC[mt] = MFMA(qal[ks], bH, qkC[mt]);
            qkC[mt] = MFMA(qah[ks], bL, qkC[mt]);
        }
    }
    // softmax over m (64 landmarks), no max-sub (|logit| < ~1)
    float p[16], dsum[4];
#pragma unroll
    for (int r = 0; r < 4; r++) dsum[r] = 0.f;
#pragma unroll
    for (int mt = 0; mt < 4; mt++)
#pragma unroll
        for (int r = 0; r < 4; r++) {
            float pv = __expf(qkC[mt][r] * SCALE);
            p[mt * 4 + r] = pv;
            dsum[r] += pv;
        }
#pragma unroll
    for (int r = 0; r < 4; r++) {
        float v = dsum[r];
        v += __shfl_xor(v, 1); v += __shfl_xor(v, 2);
        v += __shfl_xor(v, 4); v += __shfl_xor(v, 8);
        dsum[r] = 1.0f / v;
    }
    // write normalized P (split) to per-wave LDS
#pragma unroll
    for (int mt = 0; mt < 4; mt++)
#pragma unroll
        for (int r = 0; r < 4; r++) {
            float pv = p[mt * 4 + r] * dsum[r];
            u16 h, lo; split1(pv, h, lo);
            Pw[w][0][swz(hi * 4 + r, mt * 16 + c)] = h;
            Pw[w][1][swz(hi * 4 + r, mt * 16 + c)] = lo;
        }
    __syncthreads();
    // PV: out = P @ abv
    short8 pah[2], pal[2];
#pragma unroll
    for (int ks = 0; ks < 2; ks++) {
        pah[ks] = *(const short8*)&Pw[w][0][swz(c, ks * 32 + hi * 8)];
        pal[ks] = *(const short8*)&Pw[w][1][swz(c, ks * 32 + hi * 8)];
    }
    const u16* ah = abvh + bh * 4096;
    const u16* al = abvl + bh * 4096;
    floatx4 oC[4];
#pragma unroll
    for (int i = 0; i < 4; i++) oC[i] = (floatx4){0.f, 0.f, 0.f, 0.f};
#pragma unroll
    for (int dt = 0; dt < 4; dt++) {
#pragma unroll
        for (int ks = 0; ks < 2; ks++) {
            short8 bH = *(const short8*)&ah[(dt * 16 + c) * 64 + ks * 32 + hi * 8];
            short8 bL = *(const short8*)&al[(dt * 16 + c) * 64 + ks * 32 + hi * 8];
            oC[dt] = MFMA(pah[ks], bH, oC[dt]);
            oC[dt] = MFMA(pal[ks], bH, oC[dt]);
            oC[dt] = MFMA(pah[ks], bL, oC[dt]);
        }
    }
    float* ob = Og + ((size_t)bh * Ss + st * 64 + w * 16) * Dd;
#pragma unroll
    for (int dt = 0; dt < 4; dt++)
#pragma unroll
        for (int r = 0; r < 4; r++)
            ob[(hi * 4 + r) * 64 + dt * 16 + c] = oC[dt][r];
}

extern "C" void kernel_launch(void* const* d_in, const int* in_sizes, int n_in,
                              void* d_out, int out_size, void* d_ws, size_t ws_size,
                              hipStream_t stream) {
    const float* Q = (const float*)d_in[0];
    const float* K = (const float*)d_in[1];
    const float* V = (const float*)d_in[2];
    float* out = (float*)d_out;
    float* ws = (float*)d_ws;
    unsigned int* coef = (unsigned int*)d_ws;
    float* qlm  = ws + 16;
    float* klm  = qlm  + BH * Mm * Dd;
    float* smat = klm  + BH * Mm * Dd;
    float* atil = smat + BH * Mm * Mm;
    float* pnum = atil + BH * Mm * Mm;                    // [48][16][64][64]
    float* pden = pnum + (size_t)BH * NCH * Mm * Dd;      // [48][16][4][64]
    u16* ub   = (u16*)(pden + (size_t)BH * NCH * 4 * 64);
    u16* qlmh = ub;
    u16* qlml = qlmh + BH * Mm * Dd;
    u16* klmh = qlml + BH * Mm * Dd;
    u16* klml = klmh + BH * Mm * Dd;
    u16* abvh = klml + BH * Mm * Dd;
    u16* abvl = abvh + BH * Mm * Dd;

    hipMemsetAsync(d_ws, 0, 64, stream);   // coef maxes (all maxed values positive)

    k_landmarks<<<dim3(Mm, BH, 2), dim3(64), 0, stream>>>(Q, K, qlm, klm, qlmh, qlml, klmh, klml);
    k_lmsm<<<dim3(BH), dim3(256), 0, stream>>>(qlm, klm, smat, coef);
    k_pinv<<<dim3(BH), dim3(256), 5 * Mm * PST * 4, stream>>>(smat, coef, atil);
    k_bvp<<<dim3(NCH, BH), dim3(256), 0, stream>>>(K, V, qlmh, qlml, pnum, pden);
    k_bvc<<<dim3(BH), dim3(256), 0, stream>>>(pnum, pden, atil, abvh, abvl);
    k_fout<<<dim3(Ss / 64, BH), dim3(256), 0, stream>>>(Q, klmh, klml, abvh, abvl, out);
}

// Round 3
// 276.884 us; speedup vs baseline: 1.7976x; 1.0055x over previous
//
#include <hip/hip_runtime.h>
#include <math.h>

#define BH 48
#define Ss 4096
#define Dd 64
#define Mm 64
#define NCH 16
#define SCALE 0.125f
#define PST 68

typedef unsigned int u32;
typedef unsigned short u16;
typedef __attribute__((ext_vector_type(8))) short short8;
typedef __attribute__((ext_vector_type(4))) float floatx4;

union FRAG { uint4 u; short8 s; };

#define MFMA(a,b,c) __builtin_amdgcn_mfma_f32_16x16x32_bf16(a,b,c,0,0,0)

__device__ __forceinline__ u32 pack2_hi(float a, float b) {
    return (__float_as_uint(a) >> 16) | (__float_as_uint(b) & 0xFFFF0000u);
}
__device__ __forceinline__ float trunc_bf(float a) {
    return __uint_as_float(__float_as_uint(a) & 0xFFFF0000u);
}
__device__ __forceinline__ void split1(float v, u16& h, u16& l) {
    u32 u = __float_as_uint(v);
    h = (u16)(u >> 16);
    float r = v - __uint_as_float(u & 0xFFFF0000u);
    l = (u16)(__float_as_uint(r) >> 16);
}
__device__ __forceinline__ void split8(const float* v, short8& h, short8& l) {
    FRAG H, L;
    float r[8];
#pragma unroll
    for (int i = 0; i < 8; i++) r[i] = v[i] - trunc_bf(v[i]);
    H.u.x = pack2_hi(v[0], v[1]); H.u.y = pack2_hi(v[2], v[3]);
    H.u.z = pack2_hi(v[4], v[5]); H.u.w = pack2_hi(v[6], v[7]);
    L.u.x = pack2_hi(r[0], r[1]); L.u.y = pack2_hi(r[2], r[3]);
    L.u.z = pack2_hi(r[4], r[5]); L.u.w = pack2_hi(r[6], r[7]);
    h = H.s; l = L.s;
}
// XOR swizzle for [rows][64] bf16 LDS planes.
__device__ __forceinline__ int swz(int row, int col) {
    return row * 64 + ((((col >> 3) ^ (row & 7)) << 3) | (col & 7));
}

// ---------------- K1: landmarks (segment means) + bf16 hi/lo copies, float4 loads ----------------
__global__ __launch_bounds__(256) void k_landmarks(const float* __restrict__ Q,
                                                   const float* __restrict__ Kg,
                                                   float* __restrict__ qlm,
                                                   float* __restrict__ klm,
                                                   u16* __restrict__ qlmh, u16* __restrict__ qlml,
                                                   u16* __restrict__ klmh, u16* __restrict__ klml) {
    int g = blockIdx.x, bh = blockIdx.y;
    int t = threadIdx.x;
    int seg = t >> 4, d4 = t & 15;
    int m = g * 16 + seg;
    const float* src = blockIdx.z ? Kg : Q;
    float* dst = blockIdx.z ? klm : qlm;
    u16* dh = blockIdx.z ? klmh : qlmh;
    u16* dl = blockIdx.z ? klml : qlml;
    const float* base = src + ((size_t)bh * Ss + (size_t)m * 64) * Dd + d4 * 4;
    float4 acc = make_float4(0.f, 0.f, 0.f, 0.f);
#pragma unroll
    for (int l = 0; l < 64; l++) {
        float4 v = *(const float4*)(base + (size_t)l * Dd);
        acc.x += v.x; acc.y += v.y; acc.z += v.z; acc.w += v.w;
    }
    acc.x *= (1.f / 64.f); acc.y *= (1.f / 64.f);
    acc.z *= (1.f / 64.f); acc.w *= (1.f / 64.f);
    int idx = (bh * Mm + m) * Dd + d4 * 4;
    *(float4*)(dst + idx) = acc;
    float vv[4] = {acc.x, acc.y, acc.z, acc.w};
    u16 hh[4], ll[4];
#pragma unroll
    for (int i = 0; i < 4; i++) split1(vv[i], hh[i], ll[i]);
    *(uint2*)(dh + idx) = make_uint2((u32)hh[0] | ((u32)hh[1] << 16), (u32)hh[2] | ((u32)hh[3] << 16));
    *(uint2*)(dl + idx) = make_uint2((u32)ll[0] | ((u32)ll[1] << 16), (u32)ll[2] | ((u32)ll[3] << 16));
}

// ---------------- K2: landmark softmax matrix + init_coef (no per-thread big arrays) ----------------
__global__ __launch_bounds__(256) void k_lmsm(const float* __restrict__ qlm,
                                              const float* __restrict__ klm,
                                              float* __restrict__ smat,
                                              unsigned int* __restrict__ coef) {
    int bh = blockIdx.x, t = threadIdx.x;
    __shared__ float kl[Mm * Dd];
    __shared__ float ql[Mm * Dd];
    __shared__ float Lp[Mm][Mm + 1];
    const float4* kb = (const float4*)(klm + bh * Mm * Dd);
    const float4* qb = (const float4*)(qlm + bh * Mm * Dd);
    for (int i = t; i < Mm * Dd / 4; i += 256) {
        ((float4*)kl)[i] = kb[i];
        ((float4*)ql)[i] = qb[i];
    }
    __syncthreads();
    int n = t >> 2, c = t & 3;
    float p[16];
#pragma unroll
    for (int jj = 0; jj < 16; jj++) {
        int m = c * 16 + jj;
        float s = 0.f;
#pragma unroll
        for (int d4 = 0; d4 < 16; d4++) {
            int d = (((d4 + c * 4) & 15)) * 4;   // rotate so 4 c-groups hit different banks
            float4 kv = *(const float4*)(kl + m * Dd + d);
            float4 qv = *(const float4*)(ql + n * Dd + d);
            s += qv.x * kv.x + qv.y * kv.y + qv.z * kv.z + qv.w * kv.w;
        }
        p[jj] = s * SCALE;
    }
    float mx = -INFINITY;
#pragma unroll
    for (int jj = 0; jj < 16; jj++) mx = fmaxf(mx, p[jj]);
    mx = fmaxf(mx, __shfl_xor(mx, 1));
    mx = fmaxf(mx, __shfl_xor(mx, 2));
    float den = 0.f;
#pragma unroll
    for (int jj = 0; jj < 16; jj++) { p[jj] = __expf(p[jj] - mx); den += p[jj]; }
    den += __shfl_xor(den, 1);
    den += __shfl_xor(den, 2);
    float inv = 1.0f / den;
#pragma unroll
    for (int jj = 0; jj < 16; jj++) Lp[n][c * 16 + jj] = p[jj] * inv;
    __syncthreads();
    float* sg = smat + bh * Mm * Mm;
    for (int i = t; i < Mm * Mm; i += 256) sg[i] = Lp[i >> 6][i & 63];
    if (t < Mm) {
        float cs = 0.f;
#pragma unroll
        for (int nn = 0; nn < Mm; nn++) cs += Lp[nn][t];
        atomicMax(coef + 0, __float_as_uint(cs));     // max column-sum (axis=-2)
    } else if (t < 2 * Mm) {
        int nn = t - Mm; float rs = 0.f;
#pragma unroll
        for (int m = 0; m < Mm; m++) rs += Lp[nn][m];
        atomicMax(coef + 1, __float_as_uint(rs));     // max row-sum (axis=-1)
    }
}

// ---------------- K3: Newton-Schulz iterative pinv (fp32, unchanged) ----------------
__device__ __forceinline__ void mm4x4(float* __restrict__ Dm,
                                      const float* __restrict__ Am,
                                      const float* __restrict__ Bm,
                                      int ti, int tj, float diag, float sgn, float scl) {
    float acc[4][4];
#pragma unroll
    for (int a = 0; a < 4; a++)
#pragma unroll
        for (int b = 0; b < 4; b++) acc[a][b] = 0.f;
#pragma unroll
    for (int k4 = 0; k4 < 16; k4++) {
        float aa[4][4], bb[4][4];
#pragma unroll
        for (int ii = 0; ii < 4; ii++) {
            float4 v = *(const float4*)(Am + (ti + 16 * ii) * PST + k4 * 4);
            aa[ii][0] = v.x; aa[ii][1] = v.y; aa[ii][2] = v.z; aa[ii][3] = v.w;
        }
#pragma unroll
        for (int kk = 0; kk < 4; kk++) {
            float4 v = *(const float4*)(Bm + (k4 * 4 + kk) * PST + tj * 4);
            bb[kk][0] = v.x; bb[kk][1] = v.y; bb[kk][2] = v.z; bb[kk][3] = v.w;
        }
#pragma unroll
        for (int ii = 0; ii < 4; ii++)
#pragma unroll
            for (int kk = 0; kk < 4; kk++)
#pragma unroll
                for (int jj = 0; jj < 4; jj++)
                    acc[ii][jj] += aa[ii][kk] * bb[kk][jj];
    }
    int j0 = tj * 4;
#pragma unroll
    for (int ii = 0; ii < 4; ii++) {
        int i = ti + 16 * ii;
        float4 r;
        r.x = scl * (((i == j0 + 0) ? diag : 0.f) + sgn * acc[ii][0]);
        r.y = scl * (((i == j0 + 1) ? diag : 0.f) + sgn * acc[ii][1]);
        r.z = scl * (((i == j0 + 2) ? diag : 0.f) + sgn * acc[ii][2]);
        r.w = scl * (((i == j0 + 3) ? diag : 0.f) + sgn * acc[ii][3]);
        *(float4*)(Dm + i * PST + j0) = r;
    }
}

__global__ __launch_bounds__(256) void k_pinv(const float* __restrict__ smat,
                                              const unsigned int* __restrict__ coef,
                                              float* __restrict__ atil) {
    extern __shared__ float lds[];
    float* Ab = lds;
    float* B1 = Ab + Mm * PST;
    float* B2 = B1 + Mm * PST;
    float* B3 = B2 + Mm * PST;
    float* B4 = B3 + Mm * PST;
    int bh = blockIdx.x, t = threadIdx.x;
    const float* ab = smat + bh * Mm * Mm;
    for (int i = t; i < Mm * Mm; i += 256) Ab[(i >> 6) * PST + (i & 63)] = ab[i];
    __syncthreads();
    float inv = 1.0f / (__uint_as_float(coef[0]) * __uint_as_float(coef[1]));
    for (int i = t; i < Mm * Mm; i += 256) {
        int r = i >> 6, c = i & 63;
        B1[r * PST + c] = Ab[c * PST + r] * inv;
    }
    __syncthreads();
    int ti = t >> 4, tj = t & 15;
    float* Xc = B1;
    for (int it = 0; it < 6; it++) {
        float* D = (Xc == B1) ? B4 : B1;
        mm4x4(B2, Ab, Xc, ti, tj, 0.f, 1.f, 1.f);
        __syncthreads();
        for (int i = t; i < Mm * Mm; i += 256) {
            int r = i >> 6, c = i & 63;
            B3[r * PST + c] = ((r == c) ? 7.f : 0.f) - B2[r * PST + c];
        }
        __syncthreads();
        mm4x4(D, B2, B3, ti, tj, 15.f, -1.f, 1.f);
        __syncthreads();
        mm4x4(B3, B2, D, ti, tj, 13.f, -1.f, 1.f);
        __syncthreads();
        mm4x4(D, Xc, B3, ti, tj, 0.f, 1.f, 0.25f);
        __syncthreads();
        Xc = D;
    }
    float* ob = atil + bh * Mm * Mm;
    for (int i = t; i < Mm * Mm; i += 256) ob[i] = Xc[(i >> 6) * PST + (i & 63)];
}

// ---------------- K4: B_tilde @ V partials via MFMA (no max-sub; sum-combinable) ----------------
__global__ __launch_bounds__(256) void k_bvp(const float* __restrict__ Kg,
                                             const float* __restrict__ Vg,
                                             const u16* __restrict__ qlmh,
                                             const u16* __restrict__ qlml,
                                             float* __restrict__ pnum,
                                             float* __restrict__ pden) {
    __shared__ __align__(16) u16 Pb[2][4096];     // P split planes [m 64][s 64] swizzled
    __shared__ __align__(16) u16 vt[2][4096];     // V^T split planes [d 64][s 64] swizzled
    __shared__ __align__(16) float tmp[64 * 68];  // V staging f32
    int ch = blockIdx.x, bh = blockIdx.y;
    int t = threadIdx.x, w = t >> 6, l = t & 63, c = l & 15, hi = l >> 4;
    const float* Kbh = Kg + (size_t)bh * Ss * Dd;
    const float* Vbh = Vg + (size_t)bh * Ss * Dd;
    const u16* qh = qlmh + bh * Mm * Dd;
    const u16* ql = qlml + bh * Mm * Dd;
    floatx4 pvC[4];
    float denacc[16];
#pragma unroll
    for (int i = 0; i < 4; i++) pvC[i] = (floatx4){0.f, 0.f, 0.f, 0.f};
#pragma unroll
    for (int i = 0; i < 16; i++) denacc[i] = 0.f;

    for (int tile = 0; tile < 4; ++tile) {
        int s0 = ch * 256 + tile * 64;
        __syncthreads();
        // phase A: V tile -> tmp (coalesced)
        {
            int sl = t >> 2, q = (t & 3) * 16;
            const float4* vp = (const float4*)(Vbh + (size_t)(s0 + sl) * Dd + q);
            float4* dp = (float4*)(tmp + sl * 68 + q);
#pragma unroll
            for (int qq = 0; qq < 4; qq++) dp[qq] = vp[qq];
        }
        // QK^T
        {
            int srow = s0 + w * 16 + c;
            const float* kp = Kbh + (size_t)srow * Dd + hi * 8;
            short8 kbh[2], kbl[2];
#pragma unroll
            for (int ks = 0; ks < 2; ks++) {
                float kv[8];
                float4 a = *(const float4*)(kp + ks * 32);
                float4 b = *(const float4*)(kp + ks * 32 + 4);
                kv[0] = a.x; kv[1] = a.y; kv[2] = a.z; kv[3] = a.w;
                kv[4] = b.x; kv[5] = b.y; kv[6] = b.z; kv[7] = b.w;
                split8(kv, kbh[ks], kbl[ks]);
            }
            floatx4 qkC[4];
#pragma unroll
            for (int i = 0; i < 4; i++) qkC[i] = (floatx4){0.f, 0.f, 0.f, 0.f};
#pragma unroll
            for (int mt = 0; mt < 4; mt++) {
#pragma unroll
                for (int ks = 0; ks < 2; ks++) {
                    short8 aH = *(const short8*)&qh[(mt * 16 + c) * 64 + ks * 32 + hi * 8];
                    short8 aL = *(const short8*)&ql[(mt * 16 + c) * 64 + ks * 32 + hi * 8];
                    qkC[mt] = MFMA(aH, kbh[ks], qkC[mt]);
                    qkC[mt] = MFMA(aL, kbh[ks], qkC[mt]);
                    qkC[mt] = MFMA(aH, kbl[ks], qkC[mt]);
                }
            }
#pragma unroll
            for (int mt = 0; mt < 4; mt++) {
#pragma unroll
                for (int r = 0; r < 4; r++) {
                    float pv = __expf(qkC[mt][r] * SCALE);
                    denacc[mt * 4 + r] += pv;
                    int m = mt * 16 + hi * 4 + r;
                    u16 h, lo; split1(pv, h, lo);
                    Pb[0][swz(m, w * 16 + c)] = h;
                    Pb[1][swz(m, w * 16 + c)] = lo;
                }
            }
        }
        __syncthreads();
        // phase B: tmp -> vt (transpose + split)
        {
            int d = t >> 2, sg = t & 3;
            float v[16];
#pragma unroll
            for (int j = 0; j < 16; j++) v[j] = tmp[(sg * 16 + j) * 68 + d];
            short8 h0, l0, h1, l1;
            split8(v, h0, l0); split8(v + 8, h1, l1);
            *(short8*)&vt[0][swz(d, sg * 16)] = h0;
            *(short8*)&vt[0][swz(d, sg * 16 + 8)] = h1;
            *(short8*)&vt[1][swz(d, sg * 16)] = l0;
            *(short8*)&vt[1][swz(d, sg * 16 + 8)] = l1;
        }
        __syncthreads();
        // PV
#pragma unroll
        for (int ks = 0; ks < 2; ks++) {
            short8 pah = *(const short8*)&Pb[0][swz(w * 16 + c, ks * 32 + hi * 8)];
            short8 pal = *(const short8*)&Pb[1][swz(w * 16 + c, ks * 32 + hi * 8)];
#pragma unroll
            for (int dt = 0; dt < 4; dt++) {
                short8 vh = *(const short8*)&vt[0][swz(dt * 16 + c, ks * 32 + hi * 8)];
                short8 vl = *(const short8*)&vt[1][swz(dt * 16 + c, ks * 32 + hi * 8)];
                pvC[dt] = MFMA(pah, vh, pvC[dt]);
                pvC[dt] = MFMA(pal, vh, pvC[dt]);
                pvC[dt] = MFMA(pah, vl, pvC[dt]);
            }
        }
    }
    float* nb = pnum + (size_t)(bh * NCH + ch) * 4096;
#pragma unroll
    for (int dt = 0; dt < 4; dt++)
#pragma unroll
        for (int r = 0; r < 4; r++)
            nb[(w * 16 + hi * 4 + r) * 64 + dt * 16 + c] = pvC[dt][r];
#pragma unroll
    for (int i = 0; i < 16; i++) {
        float v = denacc[i];
        v += __shfl_xor(v, 1); v += __shfl_xor(v, 2);
        v += __shfl_xor(v, 4); v += __shfl_xor(v, 8);
        denacc[i] = v;
    }
    if (c == 0) {
        float* db = pden + (size_t)((bh * NCH + ch) * 4 + w) * 64;
#pragma unroll
        for (int mt = 0; mt < 4; mt++)
#pragma unroll
            for (int r = 0; r < 4; r++)
                db[mt * 16 + hi * 4 + r] = denacc[mt * 4 + r];
    }
}

// ---------------- K5: combine partials -> bv, abv = A_tilde @ bv, emit abv^T split bf16 ----------------
__global__ __launch_bounds__(256) void k_bvc(const float* __restrict__ pnum,
                                             const float* __restrict__ pden,
                                             const float* __restrict__ atil,
                                             u16* __restrict__ abvh,
                                             u16* __restrict__ abvl) {
    int bh = blockIdx.x, t = threadIdx.x;
    __shared__ float bvs[Mm][Dd + 1];
    __shared__ float Ams[Mm * (Mm + 1)];
    const float* ab = atil + bh * Mm * Mm;
    for (int i = t; i < Mm * Mm; i += 256) Ams[(i >> 6) * 65 + (i & 63)] = ab[i];
    int m = t >> 2, c = t & 3, d0 = c * 16;
    float den = 0.f;
    const float* db = pden + (size_t)bh * NCH * 4 * 64;
#pragma unroll
    for (int i = 0; i < NCH * 4; i++) den += db[i * 64 + m];
    float acc[16];
#pragma unroll
    for (int i = 0; i < 16; i++) acc[i] = 0.f;
    const float* nb = pnum + (size_t)bh * NCH * 4096;
    for (int ch = 0; ch < NCH; ch++) {
        const float4* pa = (const float4*)(nb + ch * 4096 + m * 64 + d0);
#pragma unroll
        for (int q = 0; q < 4; q++) {
            float4 v = pa[q];
            acc[q * 4 + 0] += v.x; acc[q * 4 + 1] += v.y;
            acc[q * 4 + 2] += v.z; acc[q * 4 + 3] += v.w;
        }
    }
    float inv = 1.0f / den;
#pragma unroll
    for (int ii = 0; ii < 16; ii++) bvs[m][d0 + ii] = acc[ii] * inv;
    __syncthreads();
    int j = t & 63, i0 = (t >> 6) << 4;
    float outv[16];
#pragma unroll
    for (int ii = 0; ii < 16; ii++) outv[ii] = 0.f;
#pragma unroll
    for (int k = 0; k < Mm; k++) {
        float bk = bvs[k][j];
#pragma unroll
        for (int ii = 0; ii < 16; ii++) outv[ii] += Ams[(i0 + ii) * 65 + k] * bk;
    }
    u16* oh = abvh + bh * 4096;
    u16* ol = abvl + bh * 4096;
#pragma unroll
    for (int ii = 0; ii < 16; ii++) {
        u16 h, lo; split1(outv[ii], h, lo);
        oh[j * 64 + i0 + ii] = h;    // abv^T layout [d][m]
        ol[j * 64 + i0 + ii] = lo;
    }
}

// ---------------- K6: F_tilde softmax fused with F_tilde @ abv via MFMA ----------------
__global__ __launch_bounds__(256) void k_fout(const float* __restrict__ Qg,
                                              const u16* __restrict__ klmh,
                                              const u16* __restrict__ klml,
                                              const u16* __restrict__ abvh,
                                              const u16* __restrict__ abvl,
                                              float* __restrict__ Og) {
    __shared__ __align__(16) u16 Pw[4][2][1024];   // per-wave P split planes [s 16][m 64]
    int st = blockIdx.x, bh = blockIdx.y;
    int t = threadIdx.x, w = t >> 6, l = t & 63, c = l & 15, hi = l >> 4;
    int srow = st * 64 + w * 16 + c;
    short8 qah[2], qal[2];
    {
        const float* qp = Qg + ((size_t)bh * Ss + srow) * Dd + hi * 8;
#pragma unroll
        for (int ks = 0; ks < 2; ks++) {
            float qv[8];
            float4 a = *(const float4*)(qp + ks * 32);
            float4 b = *(const float4*)(qp + ks * 32 + 4);
            qv[0] = a.x; qv[1] = a.y; qv[2] = a.z; qv[3] = a.w;
            qv[4] = b.x; qv[5] = b.y; qv[6] = b.z; qv[7] = b.w;
            split8(qv, qah[ks], qal[ks]);
        }
    }
    const u16* kh = klmh + bh * 4096;
    const u16* kl_ = klml + bh * 4096;
    floatx4 qkC[4];
#pragma unroll
    for (int i = 0; i < 4; i++) qkC[i] = (floatx4){0.f, 0.f, 0.f, 0.f};
#pragma unroll
    for (int mt = 0; mt < 4; mt++) {
#pragma unroll
        for (int ks = 0; ks < 2; ks++) {
            short8 bH = *(const short8*)&kh[(mt * 16 + c) * 64 + ks * 32 + hi * 8];
            short8 bL = *(const short8*)&kl_[(mt * 16 + c) * 64 + ks * 32 + hi * 8];
            qkC[mt] = MFMA(qah[ks], bH, qkC[mt]);
            qkC[mt] = MFMA(qal[ks], bH, qkC[mt]);
            qkC[mt] = MFMA(qah[ks], bL, qkC[mt]);
        }
    }
    float p[16], dsum[4];
#pragma unroll
    for (int r = 0; r < 4; r++) dsum[r] = 0.f;
#pragma unroll
    for (int mt = 0; mt < 4; mt++)
#pragma unroll
        for (int r = 0; r < 4; r++) {
            float pv = __expf(qkC[mt][r] * SCALE);
            p[mt * 4 + r] = pv;
            dsum[r] += pv;
        }
#pragma unroll
    for (int r = 0; r < 4; r++) {
        float v = dsum[r];
        v += __shfl_xor(v, 1); v += __shfl_xor(v, 2);
        v += __shfl_xor(v, 4); v += __shfl_xor(v, 8);
        dsum[r] = 1.0f / v;
    }
#pragma unroll
    for (int mt = 0; mt < 4; mt++)
#pragma unroll
        for (int r = 0; r < 4; r++) {
            float pv = p[mt * 4 + r] * dsum[r];
            u16 h, lo; split1(pv, h, lo);
            Pw[w][0][swz(hi * 4 + r, mt * 16 + c)] = h;
            Pw[w][1][swz(hi * 4 + r, mt * 16 + c)] = lo;
        }
    __syncthreads();
    short8 pah[2], pal[2];
#pragma unroll
    for (int ks = 0; ks < 2; ks++) {
        pah[ks] = *(const short8*)&Pw[w][0][swz(c, ks * 32 + hi * 8)];
        pal[ks] = *(const short8*)&Pw[w][1][swz(c, ks * 32 + hi * 8)];
    }
    const u16* ah = abvh + bh * 4096;
    const u16* al = abvl + bh * 4096;
    floatx4 oC[4];
#pragma unroll
    for (int i = 0; i < 4; i++) oC[i] = (floatx4){0.f, 0.f, 0.f, 0.f};
#pragma unroll
    for (int dt = 0; dt < 4; dt++) {
#pragma unroll
        for (int ks = 0; ks < 2; ks++) {
            short8 bH = *(const short8*)&ah[(dt * 16 + c) * 64 + ks * 32 + hi * 8];
            short8 bL = *(const short8*)&al[(dt * 16 + c) * 64 + ks * 32 + hi * 8];
            oC[dt] = MFMA(pah[ks], bH, oC[dt]);
            oC[dt] = MFMA(pal[ks], bH, oC[dt]);
            oC[dt] = MFMA(pah[ks], bL, oC[dt]);
        }
    }
    float* ob = Og + ((size_t)bh * Ss + st * 64 + w * 16) * Dd;
#pragma unroll
    for (int dt = 0; dt < 4; dt++)
#pragma unroll
        for (int r = 0; r < 4; r++)
            ob[(hi * 4 + r) * 64 + dt * 16 + c] = oC[dt][r];
}

extern "C" void kernel_launch(void* const* d_in, const int* in_sizes, int n_in,
                              void* d_out, int out_size, void* d_ws, size_t ws_size,
                              hipStream_t stream) {
    const float* Q = (const float*)d_in[0];
    const float* K = (const float*)d_in[1];
    const float* V = (const float*)d_in[2];
    float* out = (float*)d_out;
    float* ws = (float*)d_ws;
    unsigned int* coef = (unsigned int*)d_ws;
    float* qlm  = ws + 16;
    float* klm  = qlm  + BH * Mm * Dd;
    float* smat = klm  + BH * Mm * Dd;
    float* atil = smat + BH * Mm * Mm;
    float* pnum = atil + BH * Mm * Mm;                    // [48][16][64][64]
    float* pden = pnum + (size_t)BH * NCH * Mm * Dd;      // [48][16][4][64]
    u16* ub   = (u16*)(pden + (size_t)BH * NCH * 4 * 64);
    u16* qlmh = ub;
    u16* qlml = qlmh + BH * Mm * Dd;
    u16* klmh = qlml + BH * Mm * Dd;
    u16* klml = klmh + BH * Mm * Dd;
    u16* abvh = klml + BH * Mm * Dd;
    u16* abvl = abvh + BH * Mm * Dd;

    hipMemsetAsync(d_ws, 0, 64, stream);   // coef maxes (all maxed values positive)

    k_landmarks<<<dim3(4, BH, 2), dim3(256), 0, stream>>>(Q, K, qlm, klm, qlmh, qlml, klmh, klml);
    k_lmsm<<<dim3(BH), dim3(256), 0, stream>>>(qlm, klm, smat, coef);
    k_pinv<<<dim3(BH), dim3(256), 5 * Mm * PST * 4, stream>>>(smat, coef, atil);
    k_bvp<<<dim3(NCH, BH), dim3(256), 0, stream>>>(K, V, qlmh, qlml, pnum, pden);
    k_bvc<<<dim3(BH), dim3(256), 0, stream>>>(pnum, pden, atil, abvh, abvl);
    k_fout<<<dim3(Ss / 64, BH), dim3(256), 0, stream>>>(Q, klmh, klml, abvh, abvl, out);
}

// Round 4
// 206.941 us; speedup vs baseline: 2.4052x; 1.3380x over previous
//
#include <hip/hip_runtime.h>
#include <math.h>

#define BH 48
#define Ss 4096
#define Dd 64
#define Mm 64
#define NCH 16
#define SCALE 0.125f
#define PST 68

typedef unsigned int u32;
typedef unsigned short u16;
typedef __attribute__((ext_vector_type(8))) short short8;
typedef __attribute__((ext_vector_type(4))) float floatx4;

union FRAG { uint4 u; short8 s; };

#define MFMA(a,b,c) __builtin_amdgcn_mfma_f32_16x16x32_bf16(a,b,c,0,0,0)

__device__ __forceinline__ u32 pack2_hi(float a, float b) {
    return (__float_as_uint(a) >> 16) | (__float_as_uint(b) & 0xFFFF0000u);
}
__device__ __forceinline__ float trunc_bf(float a) {
    return __uint_as_float(__float_as_uint(a) & 0xFFFF0000u);
}
__device__ __forceinline__ void split1(float v, u16& h, u16& l) {
    u32 u = __float_as_uint(v);
    h = (u16)(u >> 16);
    float r = v - __uint_as_float(u & 0xFFFF0000u);
    l = (u16)(__float_as_uint(r) >> 16);
}
__device__ __forceinline__ void split8(const float* v, short8& h, short8& l) {
    FRAG H, L;
    float r[8];
#pragma unroll
    for (int i = 0; i < 8; i++) r[i] = v[i] - trunc_bf(v[i]);
    H.u.x = pack2_hi(v[0], v[1]); H.u.y = pack2_hi(v[2], v[3]);
    H.u.z = pack2_hi(v[4], v[5]); H.u.w = pack2_hi(v[6], v[7]);
    L.u.x = pack2_hi(r[0], r[1]); L.u.y = pack2_hi(r[2], r[3]);
    L.u.z = pack2_hi(r[4], r[5]); L.u.w = pack2_hi(r[6], r[7]);
    h = H.s; l = L.s;
}
// XOR swizzle for [rows][64] bf16 LDS planes.
__device__ __forceinline__ int swz(int row, int col) {
    return row * 64 + ((((col >> 3) ^ (row & 7)) << 3) | (col & 7));
}

// ---------------- K1: landmarks (segment means) + bf16 hi/lo copies, float4 loads ----------------
__global__ __launch_bounds__(256) void k_landmarks(const float* __restrict__ Q,
                                                   const float* __restrict__ Kg,
                                                   float* __restrict__ qlm,
                                                   float* __restrict__ klm,
                                                   u16* __restrict__ qlmh, u16* __restrict__ qlml,
                                                   u16* __restrict__ klmh, u16* __restrict__ klml) {
    int g = blockIdx.x, bh = blockIdx.y;
    int t = threadIdx.x;
    int seg = t >> 4, d4 = t & 15;
    int m = g * 16 + seg;
    const float* src = blockIdx.z ? Kg : Q;
    float* dst = blockIdx.z ? klm : qlm;
    u16* dh = blockIdx.z ? klmh : qlmh;
    u16* dl = blockIdx.z ? klml : qlml;
    const float* base = src + ((size_t)bh * Ss + (size_t)m * 64) * Dd + d4 * 4;
    float4 acc = make_float4(0.f, 0.f, 0.f, 0.f);
#pragma unroll
    for (int l = 0; l < 64; l++) {
        float4 v = *(const float4*)(base + (size_t)l * Dd);
        acc.x += v.x; acc.y += v.y; acc.z += v.z; acc.w += v.w;
    }
    acc.x *= (1.f / 64.f); acc.y *= (1.f / 64.f);
    acc.z *= (1.f / 64.f); acc.w *= (1.f / 64.f);
    int idx = (bh * Mm + m) * Dd + d4 * 4;
    *(float4*)(dst + idx) = acc;
    float vv[4] = {acc.x, acc.y, acc.z, acc.w};
    u16 hh[4], ll[4];
#pragma unroll
    for (int i = 0; i < 4; i++) split1(vv[i], hh[i], ll[i]);
    *(uint2*)(dh + idx) = make_uint2((u32)hh[0] | ((u32)hh[1] << 16), (u32)hh[2] | ((u32)hh[3] << 16));
    *(uint2*)(dl + idx) = make_uint2((u32)ll[0] | ((u32)ll[1] << 16), (u32)ll[2] | ((u32)ll[3] << 16));
}

// ---------------- K2: landmark softmax matrix + init_coef (block-reduced atomics) ----------------
__global__ __launch_bounds__(256) void k_lmsm(const float* __restrict__ qlm,
                                              const float* __restrict__ klm,
                                              float* __restrict__ smat,
                                              unsigned int* __restrict__ coef) {
    int bh = blockIdx.x, t = threadIdx.x;
    __shared__ float kl[Mm * Dd];
    __shared__ float ql[Mm * Dd];
    __shared__ float Lp[Mm][Mm + 1];
    const float4* kb = (const float4*)(klm + bh * Mm * Dd);
    const float4* qb = (const float4*)(qlm + bh * Mm * Dd);
    for (int i = t; i < Mm * Dd / 4; i += 256) {
        ((float4*)kl)[i] = kb[i];
        ((float4*)ql)[i] = qb[i];
    }
    __syncthreads();
    int n = t >> 2, c = t & 3;
    float p[16];
#pragma unroll
    for (int jj = 0; jj < 16; jj++) {
        int m = c * 16 + jj;
        float s = 0.f;
#pragma unroll
        for (int d4 = 0; d4 < 16; d4++) {
            int d = (((d4 + c * 4) & 15)) * 4;   // rotate so 4 c-groups hit different banks
            float4 kv = *(const float4*)(kl + m * Dd + d);
            float4 qv = *(const float4*)(ql + n * Dd + d);
            s += qv.x * kv.x + qv.y * kv.y + qv.z * kv.z + qv.w * kv.w;
        }
        p[jj] = s * SCALE;
    }
    float mx = -INFINITY;
#pragma unroll
    for (int jj = 0; jj < 16; jj++) mx = fmaxf(mx, p[jj]);
    mx = fmaxf(mx, __shfl_xor(mx, 1));
    mx = fmaxf(mx, __shfl_xor(mx, 2));
    float den = 0.f;
#pragma unroll
    for (int jj = 0; jj < 16; jj++) { p[jj] = __expf(p[jj] - mx); den += p[jj]; }
    den += __shfl_xor(den, 1);
    den += __shfl_xor(den, 2);
    float inv = 1.0f / den;
#pragma unroll
    for (int jj = 0; jj < 16; jj++) Lp[n][c * 16 + jj] = p[jj] * inv;
    __syncthreads();
    float* sg = smat + bh * Mm * Mm;
    for (int i = t; i < Mm * Mm; i += 256) sg[i] = Lp[i >> 6][i & 63];
    // init_coef: block-level max reduction, ONE atomic per wave (was 128/block ->
    // 6144 same-address device atomics serialized at L2 = ~83us of the old kernel)
    if (t < Mm) {                      // wave 0: column sums
        float cs = 0.f;
#pragma unroll
        for (int nn = 0; nn < Mm; nn++) cs += Lp[nn][t];
#pragma unroll
        for (int off = 1; off < 64; off <<= 1) cs = fmaxf(cs, __shfl_xor(cs, off));
        if (t == 0) atomicMax(coef + 0, __float_as_uint(cs));
    } else if (t < 2 * Mm) {           // wave 1: row sums
        int nn = t - Mm; float rs = 0.f;
#pragma unroll
        for (int m = 0; m < Mm; m++) rs += Lp[nn][m];
#pragma unroll
        for (int off = 1; off < 64; off <<= 1) rs = fmaxf(rs, __shfl_xor(rs, off));
        if (t == Mm) atomicMax(coef + 1, __float_as_uint(rs));
    }
}

// ---------------- K3: Newton-Schulz iterative pinv (fp32, unchanged) ----------------
__device__ __forceinline__ void mm4x4(float* __restrict__ Dm,
                                      const float* __restrict__ Am,
                                      const float* __restrict__ Bm,
                                      int ti, int tj, float diag, float sgn, float scl) {
    float acc[4][4];
#pragma unroll
    for (int a = 0; a < 4; a++)
#pragma unroll
        for (int b = 0; b < 4; b++) acc[a][b] = 0.f;
#pragma unroll
    for (int k4 = 0; k4 < 16; k4++) {
        float aa[4][4], bb[4][4];
#pragma unroll
        for (int ii = 0; ii < 4; ii++) {
            float4 v = *(const float4*)(Am + (ti + 16 * ii) * PST + k4 * 4);
            aa[ii][0] = v.x; aa[ii][1] = v.y; aa[ii][2] = v.z; aa[ii][3] = v.w;
        }
#pragma unroll
        for (int kk = 0; kk < 4; kk++) {
            float4 v = *(const float4*)(Bm + (k4 * 4 + kk) * PST + tj * 4);
            bb[kk][0] = v.x; bb[kk][1] = v.y; bb[kk][2] = v.z; bb[kk][3] = v.w;
        }
#pragma unroll
        for (int ii = 0; ii < 4; ii++)
#pragma unroll
            for (int kk = 0; kk < 4; kk++)
#pragma unroll
                for (int jj = 0; jj < 4; jj++)
                    acc[ii][jj] += aa[ii][kk] * bb[kk][jj];
    }
    int j0 = tj * 4;
#pragma unroll
    for (int ii = 0; ii < 4; ii++) {
        int i = ti + 16 * ii;
        float4 r;
        r.x = scl * (((i == j0 + 0) ? diag : 0.f) + sgn * acc[ii][0]);
        r.y = scl * (((i == j0 + 1) ? diag : 0.f) + sgn * acc[ii][1]);
        r.z = scl * (((i == j0 + 2) ? diag : 0.f) + sgn * acc[ii][2]);
        r.w = scl * (((i == j0 + 3) ? diag : 0.f) + sgn * acc[ii][3]);
        *(float4*)(Dm + i * PST + j0) = r;
    }
}

__global__ __launch_bounds__(256) void k_pinv(const float* __restrict__ smat,
                                              const unsigned int* __restrict__ coef,
                                              float* __restrict__ atil) {
    extern __shared__ float lds[];
    float* Ab = lds;
    float* B1 = Ab + Mm * PST;
    float* B2 = B1 + Mm * PST;
    float* B3 = B2 + Mm * PST;
    float* B4 = B3 + Mm * PST;
    int bh = blockIdx.x, t = threadIdx.x;
    const float* ab = smat + bh * Mm * Mm;
    for (int i = t; i < Mm * Mm; i += 256) Ab[(i >> 6) * PST + (i & 63)] = ab[i];
    __syncthreads();
    float inv = 1.0f / (__uint_as_float(coef[0]) * __uint_as_float(coef[1]));
    for (int i = t; i < Mm * Mm; i += 256) {
        int r = i >> 6, c = i & 63;
        B1[r * PST + c] = Ab[c * PST + r] * inv;
    }
    __syncthreads();
    int ti = t >> 4, tj = t & 15;
    float* Xc = B1;
    for (int it = 0; it < 6; it++) {
        float* D = (Xc == B1) ? B4 : B1;
        mm4x4(B2, Ab, Xc, ti, tj, 0.f, 1.f, 1.f);
        __syncthreads();
        for (int i = t; i < Mm * Mm; i += 256) {
            int r = i >> 6, c = i & 63;
            B3[r * PST + c] = ((r == c) ? 7.f : 0.f) - B2[r * PST + c];
        }
        __syncthreads();
        mm4x4(D, B2, B3, ti, tj, 15.f, -1.f, 1.f);
        __syncthreads();
        mm4x4(B3, B2, D, ti, tj, 13.f, -1.f, 1.f);
        __syncthreads();
        mm4x4(D, Xc, B3, ti, tj, 0.f, 1.f, 0.25f);
        __syncthreads();
        Xc = D;
    }
    float* ob = atil + bh * Mm * Mm;
    for (int i = t; i < Mm * Mm; i += 256) ob[i] = Xc[(i >> 6) * PST + (i & 63)];
}

// ---------------- K4: B_tilde @ V partials via MFMA (no max-sub; sum-combinable) ----------------
__global__ __launch_bounds__(256) void k_bvp(const float* __restrict__ Kg,
                                             const float* __restrict__ Vg,
                                             const u16* __restrict__ qlmh,
                                             const u16* __restrict__ qlml,
                                             float* __restrict__ pnum,
                                             float* __restrict__ pden) {
    __shared__ __align__(16) u16 Pb[2][4096];     // P split planes [m 64][s 64] swizzled
    __shared__ __align__(16) u16 vt[2][4096];     // V^T split planes [d 64][s 64] swizzled
    __shared__ __align__(16) float tmp[64 * 68];  // V staging f32
    int ch = blockIdx.x, bh = blockIdx.y;
    int t = threadIdx.x, w = t >> 6, l = t & 63, c = l & 15, hi = l >> 4;
    const float* Kbh = Kg + (size_t)bh * Ss * Dd;
    const float* Vbh = Vg + (size_t)bh * Ss * Dd;
    const u16* qh = qlmh + bh * Mm * Dd;
    const u16* ql = qlml + bh * Mm * Dd;
    floatx4 pvC[4];
    float denacc[16];
#pragma unroll
    for (int i = 0; i < 4; i++) pvC[i] = (floatx4){0.f, 0.f, 0.f, 0.f};
#pragma unroll
    for (int i = 0; i < 16; i++) denacc[i] = 0.f;

    for (int tile = 0; tile < 4; ++tile) {
        int s0 = ch * 256 + tile * 64;
        __syncthreads();
        // phase A: V tile -> tmp (coalesced)
        {
            int sl = t >> 2, q = (t & 3) * 16;
            const float4* vp = (const float4*)(Vbh + (size_t)(s0 + sl) * Dd + q);
            float4* dp = (float4*)(tmp + sl * 68 + q);
#pragma unroll
            for (int qq = 0; qq < 4; qq++) dp[qq] = vp[qq];
        }
        // QK^T
        {
            int srow = s0 + w * 16 + c;
            const float* kp = Kbh + (size_t)srow * Dd + hi * 8;
            short8 kbh[2], kbl[2];
#pragma unroll
            for (int ks = 0; ks < 2; ks++) {
                float kv[8];
                float4 a = *(const float4*)(kp + ks * 32);
                float4 b = *(const float4*)(kp + ks * 32 + 4);
                kv[0] = a.x; kv[1] = a.y; kv[2] = a.z; kv[3] = a.w;
                kv[4] = b.x; kv[5] = b.y; kv[6] = b.z; kv[7] = b.w;
                split8(kv, kbh[ks], kbl[ks]);
            }
            floatx4 qkC[4];
#pragma unroll
            for (int i = 0; i < 4; i++) qkC[i] = (floatx4){0.f, 0.f, 0.f, 0.f};
#pragma unroll
            for (int mt = 0; mt < 4; mt++) {
#pragma unroll
                for (int ks = 0; ks < 2; ks++) {
                    short8 aH = *(const short8*)&qh[(mt * 16 + c) * 64 + ks * 32 + hi * 8];
                    short8 aL = *(const short8*)&ql[(mt * 16 + c) * 64 + ks * 32 + hi * 8];
                    qkC[mt] = MFMA(aH, kbh[ks], qkC[mt]);
                    qkC[mt] = MFMA(aL, kbh[ks], qkC[mt]);
                    qkC[mt] = MFMA(aH, kbl[ks], qkC[mt]);
                }
            }
#pragma unroll
            for (int mt = 0; mt < 4; mt++) {
#pragma unroll
                for (int r = 0; r < 4; r++) {
                    float pv = __expf(qkC[mt][r] * SCALE);
                    denacc[mt * 4 + r] += pv;
                    int m = mt * 16 + hi * 4 + r;
                    u16 h, lo; split1(pv, h, lo);
                    Pb[0][swz(m, w * 16 + c)] = h;
                    Pb[1][swz(m, w * 16 + c)] = lo;
                }
            }
        }
        __syncthreads();
        // phase B: tmp -> vt (transpose + split)
        {
            int d = t >> 2, sg = t & 3;
            float v[16];
#pragma unroll
            for (int j = 0; j < 16; j++) v[j] = tmp[(sg * 16 + j) * 68 + d];
            short8 h0, l0, h1, l1;
            split8(v, h0, l0); split8(v + 8, h1, l1);
            *(short8*)&vt[0][swz(d, sg * 16)] = h0;
            *(short8*)&vt[0][swz(d, sg * 16 + 8)] = h1;
            *(short8*)&vt[1][swz(d, sg * 16)] = l0;
            *(short8*)&vt[1][swz(d, sg * 16 + 8)] = l1;
        }
        __syncthreads();
        // PV
#pragma unroll
        for (int ks = 0; ks < 2; ks++) {
            short8 pah = *(const short8*)&Pb[0][swz(w * 16 + c, ks * 32 + hi * 8)];
            short8 pal = *(const short8*)&Pb[1][swz(w * 16 + c, ks * 32 + hi * 8)];
#pragma unroll
            for (int dt = 0; dt < 4; dt++) {
                short8 vh = *(const short8*)&vt[0][swz(dt * 16 + c, ks * 32 + hi * 8)];
                short8 vl = *(const short8*)&vt[1][swz(dt * 16 + c, ks * 32 + hi * 8)];
                pvC[dt] = MFMA(pah, vh, pvC[dt]);
                pvC[dt] = MFMA(pal, vh, pvC[dt]);
                pvC[dt] = MFMA(pah, vl, pvC[dt]);
            }
        }
    }
    float* nb = pnum + (size_t)(bh * NCH + ch) * 4096;
#pragma unroll
    for (int dt = 0; dt < 4; dt++)
#pragma unroll
        for (int r = 0; r < 4; r++)
            nb[(w * 16 + hi * 4 + r) * 64 + dt * 16 + c] = pvC[dt][r];
#pragma unroll
    for (int i = 0; i < 16; i++) {
        float v = denacc[i];
        v += __shfl_xor(v, 1); v += __shfl_xor(v, 2);
        v += __shfl_xor(v, 4); v += __shfl_xor(v, 8);
        denacc[i] = v;
    }
    if (c == 0) {
        float* db = pden + (size_t)((bh * NCH + ch) * 4 + w) * 64;
#pragma unroll
        for (int mt = 0; mt < 4; mt++)
#pragma unroll
            for (int r = 0; r < 4; r++)
                db[mt * 16 + hi * 4 + r] = denacc[mt * 4 + r];
    }
}

// ---------------- K5: combine partials -> bv, abv = A_tilde @ bv, emit abv^T split bf16 ----------------
__global__ __launch_bounds__(256) void k_bvc(const float* __restrict__ pnum,
                                             const float* __restrict__ pden,
                                             const float* __restrict__ atil,
                                             u16* __restrict__ abvh,
                                             u16* __restrict__ abvl) {
    int bh = blockIdx.x, t = threadIdx.x;
    __shared__ float bvs[Mm][Dd + 1];
    __shared__ float Ams[Mm * (Mm + 1)];
    const float* ab = atil + bh * Mm * Mm;
    for (int i = t; i < Mm * Mm; i += 256) Ams[(i >> 6) * 65 + (i & 63)] = ab[i];
    int m = t >> 2, c = t & 3, d0 = c * 16;
    float den = 0.f;
    const float* db = pden + (size_t)bh * NCH * 4 * 64;
#pragma unroll
    for (int i = 0; i < NCH * 4; i++) den += db[i * 64 + m];
    float acc[16];
#pragma unroll
    for (int i = 0; i < 16; i++) acc[i] = 0.f;
    const float* nb = pnum + (size_t)bh * NCH * 4096;
    for (int ch = 0; ch < NCH; ch++) {
        const float4* pa = (const float4*)(nb + ch * 4096 + m * 64 + d0);
#pragma unroll
        for (int q = 0; q < 4; q++) {
            float4 v = pa[q];
            acc[q * 4 + 0] += v.x; acc[q * 4 + 1] += v.y;
            acc[q * 4 + 2] += v.z; acc[q * 4 + 3] += v.w;
        }
    }
    float inv = 1.0f / den;
#pragma unroll
    for (int ii = 0; ii < 16; ii++) bvs[m][d0 + ii] = acc[ii] * inv;
    __syncthreads();
    int j = t & 63, i0 = (t >> 6) << 4;
    float outv[16];
#pragma unroll
    for (int ii = 0; ii < 16; ii++) outv[ii] = 0.f;
#pragma unroll
    for (int k = 0; k < Mm; k++) {
        float bk = bvs[k][j];
#pragma unroll
        for (int ii = 0; ii < 16; ii++) outv[ii] += Ams[(i0 + ii) * 65 + k] * bk;
    }
    u16* oh = abvh + bh * 4096;
    u16* ol = abvl + bh * 4096;
#pragma unroll
    for (int ii = 0; ii < 16; ii++) {
        u16 h, lo; split1(outv[ii], h, lo);
        oh[j * 64 + i0 + ii] = h;    // abv^T layout [d][m]
        ol[j * 64 + i0 + ii] = lo;
    }
}

// ---------------- K6: F_tilde softmax fused with F_tilde @ abv via MFMA ----------------
__global__ __launch_bounds__(256) void k_fout(const float* __restrict__ Qg,
                                              const u16* __restrict__ klmh,
                                              const u16* __restrict__ klml,
                                              const u16* __restrict__ abvh,
                                              const u16* __restrict__ abvl,
                                              float* __restrict__ Og) {
    __shared__ __align__(16) u16 Pw[4][2][1024];   // per-wave P split planes [s 16][m 64]
    int st = blockIdx.x, bh = blockIdx.y;
    int t = threadIdx.x, w = t >> 6, l = t & 63, c = l & 15, hi = l >> 4;
    int srow = st * 64 + w * 16 + c;
    short8 qah[2], qal[2];
    {
        const float* qp = Qg + ((size_t)bh * Ss + srow) * Dd + hi * 8;
#pragma unroll
        for (int ks = 0; ks < 2; ks++) {
            float qv[8];
            float4 a = *(const float4*)(qp + ks * 32);
            float4 b = *(const float4*)(qp + ks * 32 + 4);
            qv[0] = a.x; qv[1] = a.y; qv[2] = a.z; qv[3] = a.w;
            qv[4] = b.x; qv[5] = b.y; qv[6] = b.z; qv[7] = b.w;
            split8(qv, qah[ks], qal[ks]);
        }
    }
    const u16* kh = klmh + bh * 4096;
    const u16* kl_ = klml + bh * 4096;
    floatx4 qkC[4];
#pragma unroll
    for (int i = 0; i < 4; i++) qkC[i] = (floatx4){0.f, 0.f, 0.f, 0.f};
#pragma unroll
    for (int mt = 0; mt < 4; mt++) {
#pragma unroll
        for (int ks = 0; ks < 2; ks++) {
            short8 bH = *(const short8*)&kh[(mt * 16 + c) * 64 + ks * 32 + hi * 8];
            short8 bL = *(const short8*)&kl_[(mt * 16 + c) * 64 + ks * 32 + hi * 8];
            qkC[mt] = MFMA(qah[ks], bH, qkC[mt]);
            qkC[mt] = MFMA(qal[ks], bH, qkC[mt]);
            qkC[mt] = MFMA(qah[ks], bL, qkC[mt]);
        }
    }
    float p[16], dsum[4];
#pragma unroll
    for (int r = 0; r < 4; r++) dsum[r] = 0.f;
#pragma unroll
    for (int mt = 0; mt < 4; mt++)
#pragma unroll
        for (int r = 0; r < 4; r++) {
            float pv = __expf(qkC[mt][r] * SCALE);
            p[mt * 4 + r] = pv;
            dsum[r] += pv;
        }
#pragma unroll
    for (int r = 0; r < 4; r++) {
        float v = dsum[r];
        v += __shfl_xor(v, 1); v += __shfl_xor(v, 2);
        v += __shfl_xor(v, 4); v += __shfl_xor(v, 8);
        dsum[r] = 1.0f / v;
    }
#pragma unroll
    for (int mt = 0; mt < 4; mt++)
#pragma unroll
        for (int r = 0; r < 4; r++) {
            float pv = p[mt * 4 + r] * dsum[r];
            u16 h, lo; split1(pv, h, lo);
            Pw[w][0][swz(hi * 4 + r, mt * 16 + c)] = h;
            Pw[w][1][swz(hi * 4 + r, mt * 16 + c)] = lo;
        }
    __syncthreads();
    short8 pah[2], pal[2];
#pragma unroll
    for (int ks = 0; ks < 2; ks++) {
        pah[ks] = *(const short8*)&Pw[w][0][swz(c, ks * 32 + hi * 8)];
        pal[ks] = *(const short8*)&Pw[w][1][swz(c, ks * 32 + hi * 8)];
    }
    const u16* ah = abvh + bh * 4096;
    const u16* al = abvl + bh * 4096;
    floatx4 oC[4];
#pragma unroll
    for (int i = 0; i < 4; i++) oC[i] = (floatx4){0.f, 0.f, 0.f, 0.f};
#pragma unroll
    for (int dt = 0; dt < 4; dt++) {
#pragma unroll
        for (int ks = 0; ks < 2; ks++) {
            short8 bH = *(const short8*)&ah[(dt * 16 + c) * 64 + ks * 32 + hi * 8];
            short8 bL = *(const short8*)&al[(dt * 16 + c) * 64 + ks * 32 + hi * 8];
            oC[dt] = MFMA(pah[ks], bH, oC[dt]);
            oC[dt] = MFMA(pal[ks], bH, oC[dt]);
            oC[dt] = MFMA(pah[ks], bL, oC[dt]);
        }
    }
    float* ob = Og + ((size_t)bh * Ss + st * 64 + w * 16) * Dd;
#pragma unroll
    for (int dt = 0; dt < 4; dt++)
#pragma unroll
        for (int r = 0; r < 4; r++)
            ob[(hi * 4 + r) * 64 + dt * 16 + c] = oC[dt][r];
}

extern "C" void kernel_launch(void* const* d_in, const int* in_sizes, int n_in,
                              void* d_out, int out_size, void* d_ws, size_t ws_size,
                              hipStream_t stream) {
    const float* Q = (const float*)d_in[0];
    const float* K = (const float*)d_in[1];
    const float* V = (const float*)d_in[2];
    float* out = (float*)d_out;
    float* ws = (float*)d_ws;
    unsigned int* coef = (unsigned int*)d_ws;
    float* qlm  = ws + 16;
    float* klm  = qlm  + BH * Mm * Dd;
    float* smat = klm  + BH * Mm * Dd;
    float* atil = smat + BH * Mm * Mm;
    float* pnum = atil + BH * Mm * Mm;                    // [48][16][64][64]
    float* pden = pnum + (size_t)BH * NCH * Mm * Dd;      // [48][16][4][64]
    u16* ub   = (u16*)(pden + (size_t)BH * NCH * 4 * 64);
    u16* qlmh = ub;
    u16* qlml = qlmh + BH * Mm * Dd;
    u16* klmh = qlml + BH * Mm * Dd;
    u16* klml = klmh + BH * Mm * Dd;
    u16* abvh = klml + BH * Mm * Dd;
    u16* abvl = abvh + BH * Mm * Dd;

    hipMemsetAsync(d_ws, 0, 64, stream);   // coef maxes (all maxed values positive)

    k_landmarks<<<dim3(4, BH, 2), dim3(256), 0, stream>>>(Q, K, qlm, klm, qlmh, qlml, klmh, klml);
    k_lmsm<<<dim3(BH), dim3(256), 0, stream>>>(qlm, klm, smat, coef);
    k_pinv<<<dim3(BH), dim3(256), 5 * Mm * PST * 4, stream>>>(smat, coef, atil);
    k_bvp<<<dim3(NCH, BH), dim3(256), 0, stream>>>(K, V, qlmh, qlml, pnum, pden);
    k_bvc<<<dim3(BH), dim3(256), 0, stream>>>(pnum, pden, atil, abvh, abvl);
    k_fout<<<dim3(Ss / 64, BH), dim3(256), 0, stream>>>(Q, klmh, klml, abvh, abvl, out);
}

// Round 6
// 175.427 us; speedup vs baseline: 2.8373x; 1.1796x over previous
//
#include <hip/hip_runtime.h>
#include <math.h>

#define BH 48
#define Ss 4096
#define Dd 64
#define Mm 64
#define NCH 16
#define SCALE 0.125f
#define PLN 4096

typedef unsigned int u32;
typedef unsigned short u16;
typedef __attribute__((ext_vector_type(8))) short short8;
typedef __attribute__((ext_vector_type(4))) float floatx4;

union FRAG { uint4 u; short8 s; };

#define MFMA(a,b,c) __builtin_amdgcn_mfma_f32_16x16x32_bf16(a,b,c,0,0,0)

__device__ __forceinline__ u32 pack2_hi(float a, float b) {
    return (__float_as_uint(a) >> 16) | (__float_as_uint(b) & 0xFFFF0000u);
}
__device__ __forceinline__ float trunc_bf(float a) {
    return __uint_as_float(__float_as_uint(a) & 0xFFFF0000u);
}
__device__ __forceinline__ void split1(float v, u16& h, u16& l) {
    u32 u = __float_as_uint(v);
    h = (u16)(u >> 16);
    float r = v - __uint_as_float(u & 0xFFFF0000u);
    l = (u16)(__float_as_uint(r) >> 16);
}
__device__ __forceinline__ void split8(const float* v, short8& h, short8& l) {
    FRAG H, L;
    float r[8];
#pragma unroll
    for (int i = 0; i < 8; i++) r[i] = v[i] - trunc_bf(v[i]);
    H.u.x = pack2_hi(v[0], v[1]); H.u.y = pack2_hi(v[2], v[3]);
    H.u.z = pack2_hi(v[4], v[5]); H.u.w = pack2_hi(v[6], v[7]);
    L.u.x = pack2_hi(r[0], r[1]); L.u.y = pack2_hi(r[2], r[3]);
    L.u.z = pack2_hi(r[4], r[5]); L.u.w = pack2_hi(r[6], r[7]);
    h = H.s; l = L.s;
}
// XOR swizzle for [rows][64] bf16 LDS planes.
__device__ __forceinline__ int swz(int row, int col) {
    return row * 64 + ((((col >> 3) ^ (row & 7)) << 3) | (col & 7));
}

// ---------------- K1: landmarks (segment means) + bf16 hi/lo copies, float4 loads ----------------
__global__ __launch_bounds__(256) void k_landmarks(const float* __restrict__ Q,
                                                   const float* __restrict__ Kg,
                                                   float* __restrict__ qlm,
                                                   float* __restrict__ klm,
                                                   u16* __restrict__ qlmh, u16* __restrict__ qlml,
                                                   u16* __restrict__ klmh, u16* __restrict__ klml) {
    int g = blockIdx.x, bh = blockIdx.y;
    int t = threadIdx.x;
    int seg = t >> 4, d4 = t & 15;
    int m = g * 16 + seg;
    const float* src = blockIdx.z ? Kg : Q;
    float* dst = blockIdx.z ? klm : qlm;
    u16* dh = blockIdx.z ? klmh : qlmh;
    u16* dl = blockIdx.z ? klml : qlml;
    const float* base = src + ((size_t)bh * Ss + (size_t)m * 64) * Dd + d4 * 4;
    float4 acc = make_float4(0.f, 0.f, 0.f, 0.f);
#pragma unroll
    for (int l = 0; l < 64; l++) {
        float4 v = *(const float4*)(base + (size_t)l * Dd);
        acc.x += v.x; acc.y += v.y; acc.z += v.z; acc.w += v.w;
    }
    acc.x *= (1.f / 64.f); acc.y *= (1.f / 64.f);
    acc.z *= (1.f / 64.f); acc.w *= (1.f / 64.f);
    int idx = (bh * Mm + m) * Dd + d4 * 4;
    *(float4*)(dst + idx) = acc;
    float vv[4] = {acc.x, acc.y, acc.z, acc.w};
    u16 hh[4], ll[4];
#pragma unroll
    for (int i = 0; i < 4; i++) split1(vv[i], hh[i], ll[i]);
    *(uint2*)(dh + idx) = make_uint2((u32)hh[0] | ((u32)hh[1] << 16), (u32)hh[2] | ((u32)hh[3] << 16));
    *(uint2*)(dl + idx) = make_uint2((u32)ll[0] | ((u32)ll[1] << 16), (u32)ll[2] | ((u32)ll[3] << 16));
}

// ---------------- K2: landmark softmax matrix + init_coef (block-reduced atomics) ----------------
__global__ __launch_bounds__(256) void k_lmsm(const float* __restrict__ qlm,
                                              const float* __restrict__ klm,
                                              float* __restrict__ smat,
                                              unsigned int* __restrict__ coef) {
    int bh = blockIdx.x, t = threadIdx.x;
    __shared__ float kl[Mm * Dd];
    __shared__ float ql[Mm * Dd];
    __shared__ float Lp[Mm][Mm + 1];
    const float4* kb = (const float4*)(klm + bh * Mm * Dd);
    const float4* qb = (const float4*)(qlm + bh * Mm * Dd);
    for (int i = t; i < Mm * Dd / 4; i += 256) {
        ((float4*)kl)[i] = kb[i];
        ((float4*)ql)[i] = qb[i];
    }
    __syncthreads();
    int n = t >> 2, c = t & 3;
    float p[16];
#pragma unroll
    for (int jj = 0; jj < 16; jj++) {
        int m = c * 16 + jj;
        float s = 0.f;
#pragma unroll
        for (int d4 = 0; d4 < 16; d4++) {
            int d = (((d4 + c * 4) & 15)) * 4;
            float4 kv = *(const float4*)(kl + m * Dd + d);
            float4 qv = *(const float4*)(ql + n * Dd + d);
            s += qv.x * kv.x + qv.y * kv.y + qv.z * kv.z + qv.w * kv.w;
        }
        p[jj] = s * SCALE;
    }
    float mx = -INFINITY;
#pragma unroll
    for (int jj = 0; jj < 16; jj++) mx = fmaxf(mx, p[jj]);
    mx = fmaxf(mx, __shfl_xor(mx, 1));
    mx = fmaxf(mx, __shfl_xor(mx, 2));
    float den = 0.f;
#pragma unroll
    for (int jj = 0; jj < 16; jj++) { p[jj] = __expf(p[jj] - mx); den += p[jj]; }
    den += __shfl_xor(den, 1);
    den += __shfl_xor(den, 2);
    float inv = 1.0f / den;
#pragma unroll
    for (int jj = 0; jj < 16; jj++) Lp[n][c * 16 + jj] = p[jj] * inv;
    __syncthreads();
    float* sg = smat + bh * Mm * Mm;
    for (int i = t; i < Mm * Mm; i += 256) sg[i] = Lp[i >> 6][i & 63];
    if (t < Mm) {
        float cs = 0.f;
#pragma unroll
        for (int nn = 0; nn < Mm; nn++) cs += Lp[nn][t];
#pragma unroll
        for (int off = 1; off < 64; off <<= 1) cs = fmaxf(cs, __shfl_xor(cs, off));
        if (t == 0) atomicMax(coef + 0, __float_as_uint(cs));
    } else if (t < 2 * Mm) {
        int nn = t - Mm; float rs = 0.f;
#pragma unroll
        for (int m = 0; m < Mm; m++) rs += Lp[nn][m];
#pragma unroll
        for (int off = 1; off < 64; off <<= 1) rs = fmaxf(rs, __shfl_xor(rs, off));
        if (t == Mm) atomicMax(coef + 1, __float_as_uint(rs));
    }
}

// ---------------- K3: Newton-Schulz pinv via split-bf16 MFMA ----------------
// All matrices live in LDS as swizzled bf16 hi/lo plane pairs in "fragment
// layout" F[r][k]. mfma pass with A-op from Fa, B-op from Fb computes
// D[i][j] = sum_k Fa[i][k]*Fb[j][k] and naturally writes Fout[j][i] = D[i][j],
// i.e. Fout = Fb @ Fa^T (row-major views). Choosing operand order per pass
// yields every intermediate directly in its consumer's layout (no transposes).
__device__ __forceinline__ void pinv_pass(const u16* __restrict__ Ah, const u16* __restrict__ Al,
                                          const u16* __restrict__ Bph, const u16* __restrict__ Bpl,
                                          u16* __restrict__ Oh, u16* __restrict__ Ol,
                                          int w, int c, int hi,
                                          float diag, float sgn, float scl) {
    short8 bfh[2], bfl[2];
#pragma unroll
    for (int ks = 0; ks < 2; ks++) {
        bfh[ks] = *(const short8*)&Bph[swz(w * 16 + c, ks * 32 + hi * 8)];
        bfl[ks] = *(const short8*)&Bpl[swz(w * 16 + c, ks * 32 + hi * 8)];
    }
    int j = w * 16 + c;
#pragma unroll
    for (int ta = 0; ta < 4; ta++) {
        floatx4 acc = (floatx4){0.f, 0.f, 0.f, 0.f};
#pragma unroll
        for (int ks = 0; ks < 2; ks++) {
            short8 afh = *(const short8*)&Ah[swz(ta * 16 + c, ks * 32 + hi * 8)];
            short8 afl = *(const short8*)&Al[swz(ta * 16 + c, ks * 32 + hi * 8)];
            acc = MFMA(afh, bfh[ks], acc);
            acc = MFMA(afl, bfh[ks], acc);
            acc = MFMA(afh, bfl[ks], acc);
        }
        u16 oh[4], ol[4];
#pragma unroll
        for (int r = 0; r < 4; r++) {
            int i = ta * 16 + hi * 4 + r;
            float v = scl * (((i == j) ? diag : 0.f) + sgn * acc[r]);
            split1(v, oh[r], ol[r]);
        }
        int o0 = swz(j, ta * 16 + hi * 4);
        *(u32*)&Oh[o0]     = (u32)oh[0] | ((u32)oh[1] << 16);
        *(u32*)&Oh[o0 + 2] = (u32)oh[2] | ((u32)oh[3] << 16);
        *(u32*)&Ol[o0]     = (u32)ol[0] | ((u32)ol[1] << 16);
        *(u32*)&Ol[o0 + 2] = (u32)ol[2] | ((u32)ol[3] << 16);
    }
}

__global__ __launch_bounds__(256) void k_pinv(const float* __restrict__ smat,
                                              const unsigned int* __restrict__ coef,
                                              float* __restrict__ atil) {
    extern __shared__ u16 P[];
    u16* FaH  = P;             u16* FaL  = P + PLN;       // A        (row-major A)
    u16* FxcH = P + 2 * PLN;   u16* FxcL = P + 3 * PLN;   // X^T      (= A*inv)
    u16* X0H  = P + 4 * PLN;   u16* X0L  = P + 5 * PLN;   // X row-major (ping)
    u16* X1H  = P + 6 * PLN;   u16* X1L  = P + 7 * PLN;   // mo / X row-major (pong)
    u16* T1H  = P + 8 * PLN;   u16* T1L  = P + 9 * PLN;   // t1^T / t3^T
    u16* T2H  = P + 10 * PLN;  u16* T2L  = P + 11 * PLN;  // t2^T
    int bh = blockIdx.x, t = threadIdx.x;
    int w = t >> 6, l = t & 63, c = l & 15, hi = l >> 4;
    float inv = 1.0f / (__uint_as_float(coef[0]) * __uint_as_float(coef[1]));
    {   // prologue: load A, build Fa, Fxc (=A*inv), X row-major (scatter)
        int r = t >> 2, kq = (t & 3) * 16;
        const float* ar = smat + bh * 4096 + r * 64 + kq;
        float v[16];
#pragma unroll
        for (int q = 0; q < 4; q++) {
            float4 x = *(const float4*)(ar + q * 4);
            v[q * 4 + 0] = x.x; v[q * 4 + 1] = x.y; v[q * 4 + 2] = x.z; v[q * 4 + 3] = x.w;
        }
        short8 h0, l0, h1, l1;
        split8(v, h0, l0); split8(v + 8, h1, l1);
        *(short8*)&FaH[swz(r, kq)] = h0;     *(short8*)&FaH[swz(r, kq + 8)] = h1;
        *(short8*)&FaL[swz(r, kq)] = l0;     *(short8*)&FaL[swz(r, kq + 8)] = l1;
        float vs[16];
#pragma unroll
        for (int q = 0; q < 16; q++) vs[q] = v[q] * inv;
        split8(vs, h0, l0); split8(vs + 8, h1, l1);
        *(short8*)&FxcH[swz(r, kq)] = h0;    *(short8*)&FxcH[swz(r, kq + 8)] = h1;
        *(short8*)&FxcL[swz(r, kq)] = l0;    *(short8*)&FxcL[swz(r, kq + 8)] = l1;
#pragma unroll
        for (int q = 0; q < 16; q++) {       // X[kq+q][r] = A[r][kq+q]*inv
            u16 h, lo; split1(vs[q], h, lo);
            X0H[swz(kq + q, r)] = h;
            X0L[swz(kq + q, r)] = lo;
        }
    }
    __syncthreads();
    u16 *xrH = X0H, *xrL = X0L, *moH = X1H, *moL = X1L;
    for (int it = 0; it < 6; it++) {
        pinv_pass(FxcH, FxcL, FaH, FaL, moH, moL, w, c, hi, 0.f, 1.f, 1.f);    // mo = A@X  (row-major)
        pinv_pass(FaH, FaL, FxcH, FxcL, T1H, T1L, w, c, hi, 7.f, -1.f, 1.f);   // t1^T = 7I - mo^T
        __syncthreads();
        pinv_pass(moH, moL, T1H, T1L, T2H, T2L, w, c, hi, 15.f, -1.f, 1.f);    // t2^T = 15I - (mo@t1)^T
        __syncthreads();
        pinv_pass(moH, moL, T2H, T2L, T1H, T1L, w, c, hi, 13.f, -1.f, 1.f);    // t3^T = 13I - (mo@t2)^T
        __syncthreads();
        pinv_pass(T1H, T1L, xrH, xrL, moH, moL, w, c, hi, 0.f, 1.f, 0.25f);    // X' = 0.25 X@t3 (row-major, into mo buf)
        pinv_pass(xrH, xrL, T1H, T1L, FxcH, FxcL, w, c, hi, 0.f, 1.f, 0.25f);  // X'^T into Fxc
        __syncthreads();
        u16* th = xrH; xrH = moH; moH = th;
        u16* tl = xrL; xrL = moL; moL = tl;
    }
    {   // epilogue: atil[i][j] = X[i][j] (hi+lo reconstruct)
        int i = t >> 2, j0 = (t & 3) * 16;
        FRAG h0, l0, h1, l1;
        h0.s = *(const short8*)&xrH[swz(i, j0)];
        l0.s = *(const short8*)&xrL[swz(i, j0)];
        h1.s = *(const short8*)&xrH[swz(i, j0 + 8)];
        l1.s = *(const short8*)&xrL[swz(i, j0 + 8)];
        float* ob = atil + bh * 4096 + i * 64 + j0;
#pragma unroll
        for (int q = 0; q < 8; q++) {
            ob[q]     = __uint_as_float(((u32)(u16)h0.s[q]) << 16) + __uint_as_float(((u32)(u16)l0.s[q]) << 16);
            ob[q + 8] = __uint_as_float(((u32)(u16)h1.s[q]) << 16) + __uint_as_float(((u32)(u16)l1.s[q]) << 16);
        }
    }
}

// ---------------- K4: B_tilde @ V partials via MFMA (no max-sub; sum-combinable) ----------------
__global__ __launch_bounds__(256) void k_bvp(const float* __restrict__ Kg,
                                             const float* __restrict__ Vg,
                                             const u16* __restrict__ qlmh,
                                             const u16* __restrict__ qlml,
                                             float* __restrict__ pnum,
                                             float* __restrict__ pden) {
    __shared__ __align__(16) u16 Pb[2][4096];     // P split planes [m 64][s 64] swizzled
    __shared__ __align__(16) u16 vt[2][4096];     // V^T split planes [d 64][s 64] swizzled
    __shared__ __align__(16) float tmp[64 * 68];  // V staging f32
    int ch = blockIdx.x, bh = blockIdx.y;
    int t = threadIdx.x, w = t >> 6, l = t & 63, c = l & 15, hi = l >> 4;
    const float* Kbh = Kg + (size_t)bh * Ss * Dd;
    const float* Vbh = Vg + (size_t)bh * Ss * Dd;
    const u16* qh = qlmh + bh * Mm * Dd;
    const u16* ql = qlml + bh * Mm * Dd;
    floatx4 pvC[4];
    float denacc[16];
#pragma unroll
    for (int i = 0; i < 4; i++) pvC[i] = (floatx4){0.f, 0.f, 0.f, 0.f};
#pragma unroll
    for (int i = 0; i < 16; i++) denacc[i] = 0.f;

    for (int tile = 0; tile < 4; ++tile) {
        int s0 = ch * 256 + tile * 64;
        __syncthreads();
        // phase A: V tile -> tmp (coalesced)
        {
            int sl = t >> 2, q = (t & 3) * 16;
            const float4* vp = (const float4*)(Vbh + (size_t)(s0 + sl) * Dd + q);
            float4* dp = (float4*)(tmp + sl * 68 + q);
#pragma unroll
            for (int qq = 0; qq < 4; qq++) dp[qq] = vp[qq];
        }
        // QK^T
        {
            int srow = s0 + w * 16 + c;
            const float* kp = Kbh + (size_t)srow * Dd + hi * 8;
            short8 kbh[2], kbl[2];
#pragma unroll
            for (int ks = 0; ks < 2; ks++) {
                float kv[8];
                float4 a = *(const float4*)(kp + ks * 32);
                float4 b = *(const float4*)(kp + ks * 32 + 4);
                kv[0] = a.x; kv[1] = a.y; kv[2] = a.z; kv[3] = a.w;
                kv[4] = b.x; kv[5] = b.y; kv[6] = b.z; kv[7] = b.w;
                split8(kv, kbh[ks], kbl[ks]);
            }
            floatx4 qkC[4];
#pragma unroll
            for (int i = 0; i < 4; i++) qkC[i] = (floatx4){0.f, 0.f, 0.f, 0.f};
#pragma unroll
            for (int mt = 0; mt < 4; mt++) {
#pragma unroll
                for (int ks = 0; ks < 2; ks++) {
                    short8 aH = *(const short8*)&qh[(mt * 16 + c) * 64 + ks * 32 + hi * 8];
                    short8 aL = *(const short8*)&ql[(mt * 16 + c) * 64 + ks * 32 + hi * 8];
                    qkC[mt] = MFMA(aH, kbh[ks], qkC[mt]);
                    qkC[mt] = MFMA(aL, kbh[ks], qkC[mt]);
                    qkC[mt] = MFMA(aH, kbl[ks], qkC[mt]);
                }
            }
#pragma unroll
            for (int mt = 0; mt < 4; mt++) {
#pragma unroll
                for (int r = 0; r < 4; r++) {
                    float pv = __expf(qkC[mt][r] * SCALE);
                    denacc[mt * 4 + r] += pv;
                    int m = mt * 16 + hi * 4 + r;
                    u16 h, lo; split1(pv, h, lo);
                    Pb[0][swz(m, w * 16 + c)] = h;
                    Pb[1][swz(m, w * 16 + c)] = lo;
                }
            }
        }
        __syncthreads();
        // phase B: tmp -> vt (transpose + split)
        {
            int d = t >> 2, sg = t & 3;
            float v[16];
#pragma unroll
            for (int j = 0; j < 16; j++) v[j] = tmp[(sg * 16 + j) * 68 + d];
            short8 h0, l0, h1, l1;
            split8(v, h0, l0); split8(v + 8, h1, l1);
            *(short8*)&vt[0][swz(d, sg * 16)] = h0;
            *(short8*)&vt[0][swz(d, sg * 16 + 8)] = h1;
            *(short8*)&vt[1][swz(d, sg * 16)] = l0;
            *(short8*)&vt[1][swz(d, sg * 16 + 8)] = l1;
        }
        __syncthreads();
        // PV
#pragma unroll
        for (int ks = 0; ks < 2; ks++) {
            short8 pah = *(const short8*)&Pb[0][swz(w * 16 + c, ks * 32 + hi * 8)];
            short8 pal = *(const short8*)&Pb[1][swz(w * 16 + c, ks * 32 + hi * 8)];
#pragma unroll
            for (int dt = 0; dt < 4; dt++) {
                short8 vh = *(const short8*)&vt[0][swz(dt * 16 + c, ks * 32 + hi * 8)];
                short8 vl = *(const short8*)&vt[1][swz(dt * 16 + c, ks * 32 + hi * 8)];
                pvC[dt] = MFMA(pah, vh, pvC[dt]);
                pvC[dt] = MFMA(pal, vh, pvC[dt]);
                pvC[dt] = MFMA(pah, vl, pvC[dt]);
            }
        }
    }
    float* nb = pnum + (size_t)(bh * NCH + ch) * 4096;
#pragma unroll
    for (int dt = 0; dt < 4; dt++)
#pragma unroll
        for (int r = 0; r < 4; r++)
            nb[(w * 16 + hi * 4 + r) * 64 + dt * 16 + c] = pvC[dt][r];
#pragma unroll
    for (int i = 0; i < 16; i++) {
        float v = denacc[i];
        v += __shfl_xor(v, 1); v += __shfl_xor(v, 2);
        v += __shfl_xor(v, 4); v += __shfl_xor(v, 8);
        denacc[i] = v;
    }
    if (c == 0) {
        float* db = pden + (size_t)((bh * NCH + ch) * 4 + w) * 64;
#pragma unroll
        for (int mt = 0; mt < 4; mt++)
#pragma unroll
            for (int r = 0; r < 4; r++)
                db[mt * 16 + hi * 4 + r] = denacc[mt * 4 + r];
    }
}

// ---------------- K5: combine partials -> bv, abv = A_tilde @ bv, emit abv^T split bf16 ----------------
__global__ __launch_bounds__(256) void k_bvc(const float* __restrict__ pnum,
                                             const float* __restrict__ pden,
                                             const float* __restrict__ atil,
                                             u16* __restrict__ abvh,
                                             u16* __restrict__ abvl) {
    int bh = blockIdx.x, t = threadIdx.x;
    __shared__ float bvs[Mm][Dd + 1];
    __shared__ float Ams[Mm * (Mm + 1)];
    const float* ab = atil + bh * Mm * Mm;
    for (int i = t; i < Mm * Mm; i += 256) Ams[(i >> 6) * 65 + (i & 63)] = ab[i];
    int m = t >> 2, c = t & 3, d0 = c * 16;
    float den = 0.f;
    const float* db = pden + (size_t)bh * NCH * 4 * 64;
#pragma unroll
    for (int i = 0; i < NCH * 4; i++) den += db[i * 64 + m];
    float acc[16];
#pragma unroll
    for (int i = 0; i < 16; i++) acc[i] = 0.f;
    const float* nb = pnum + (size_t)bh * NCH * 4096;
    for (int ch = 0; ch < NCH; ch++) {
        const float4* pa = (const float4*)(nb + ch * 4096 + m * 64 + d0);
#pragma unroll
        for (int q = 0; q < 4; q++) {
            float4 v = pa[q];
            acc[q * 4 + 0] += v.x; acc[q * 4 + 1] += v.y;
            acc[q * 4 + 2] += v.z; acc[q * 4 + 3] += v.w;
        }
    }
    float inv = 1.0f / den;
#pragma unroll
    for (int ii = 0; ii < 16; ii++) bvs[m][d0 + ii] = acc[ii] * inv;
    __syncthreads();
    int j = t & 63, i0 = (t >> 6) << 4;
    float outv[16];
#pragma unroll
    for (int ii = 0; ii < 16; ii++) outv[ii] = 0.f;
#pragma unroll
    for (int k = 0; k < Mm; k++) {
        float bk = bvs[k][j];
#pragma unroll
        for (int ii = 0; ii < 16; ii++) outv[ii] += Ams[(i0 + ii) * 65 + k] * bk;
    }
    u16* oh = abvh + bh * 4096;
    u16* ol = abvl + bh * 4096;
#pragma unroll
    for (int ii = 0; ii < 16; ii++) {
        u16 h, lo; split1(outv[ii], h, lo);
        oh[j * 64 + i0 + ii] = h;    // abv^T layout [d][m]
        ol[j * 64 + i0 + ii] = lo;
    }
}

// ---------------- K6: F_tilde softmax fused with F_tilde @ abv via MFMA ----------------
__global__ __launch_bounds__(256) void k_fout(const float* __restrict__ Qg,
                                              const u16* __restrict__ klmh,
                                              const u16* __restrict__ klml,
                                              const u16* __restrict__ abvh,
                                              const u16* __restrict__ abvl,
                                              float* __restrict__ Og) {
    __shared__ __align__(16) u16 Pw[4][2][1024];   // per-wave P split planes [s 16][m 64]
    int st = blockIdx.x, bh = blockIdx.y;
    int t = threadIdx.x, w = t >> 6, l = t & 63, c = l & 15, hi = l >> 4;
    int srow = st * 64 + w * 16 + c;
    short8 qah[2], qal[2];
    {
        const float* qp = Qg + ((size_t)bh * Ss + srow) * Dd + hi * 8;
#pragma unroll
        for (int ks = 0; ks < 2; ks++) {
            float qv[8];
            float4 a = *(const float4*)(qp + ks * 32);
            float4 b = *(const float4*)(qp + ks * 32 + 4);
            qv[0] = a.x; qv[1] = a.y; qv[2] = a.z; qv[3] = a.w;
            qv[4] = b.x; qv[5] = b.y; qv[6] = b.z; qv[7] = b.w;
            split8(qv, qah[ks], qal[ks]);
        }
    }
    const u16* kh = klmh + bh * 4096;
    const u16* kl_ = klml + bh * 4096;
    floatx4 qkC[4];
#pragma unroll
    for (int i = 0; i < 4; i++) qkC[i] = (floatx4){0.f, 0.f, 0.f, 0.f};
#pragma unroll
    for (int mt = 0; mt < 4; mt++) {
#pragma unroll
        for (int ks = 0; ks < 2; ks++) {
            short8 bH = *(const short8*)&kh[(mt * 16 + c) * 64 + ks * 32 + hi * 8];
            short8 bL = *(const short8*)&kl_[(mt * 16 + c) * 64 + ks * 32 + hi * 8];
            qkC[mt] = MFMA(qah[ks], bH, qkC[mt]);
            qkC[mt] = MFMA(qal[ks], bH, qkC[mt]);
            qkC[mt] = MFMA(qah[ks], bL, qkC[mt]);
        }
    }
    float p[16], dsum[4];
#pragma unroll
    for (int r = 0; r < 4; r++) dsum[r] = 0.f;
#pragma unroll
    for (int mt = 0; mt < 4; mt++)
#pragma unroll
        for (int r = 0; r < 4; r++) {
            float pv = __expf(qkC[mt][r] * SCALE);
            p[mt * 4 + r] = pv;
            dsum[r] += pv;
        }
#pragma unroll
    for (int r = 0; r < 4; r++) {
        float v = dsum[r];
        v += __shfl_xor(v, 1); v += __shfl_xor(v, 2);
        v += __shfl_xor(v, 4); v += __shfl_xor(v, 8);
        dsum[r] = 1.0f / v;
    }
#pragma unroll
    for (int mt = 0; mt < 4; mt++)
#pragma unroll
        for (int r = 0; r < 4; r++) {
            float pv = p[mt * 4 + r] * dsum[r];
            u16 h, lo; split1(pv, h, lo);
            Pw[w][0][swz(hi * 4 + r, mt * 16 + c)] = h;
            Pw[w][1][swz(hi * 4 + r, mt * 16 + c)] = lo;
        }
    __syncthreads();
    short8 pah[2], pal[2];
#pragma unroll
    for (int ks = 0; ks < 2; ks++) {
        pah[ks] = *(const short8*)&Pw[w][0][swz(c, ks * 32 + hi * 8)];
        pal[ks] = *(const short8*)&Pw[w][1][swz(c, ks * 32 + hi * 8)];
    }
    const u16* ah = abvh + bh * 4096;
    const u16* al = abvl + bh * 4096;
    floatx4 oC[4];
#pragma unroll
    for (int i = 0; i < 4; i++) oC[i] = (floatx4){0.f, 0.f, 0.f, 0.f};
#pragma unroll
    for (int dt = 0; dt < 4; dt++) {
#pragma unroll
        for (int ks = 0; ks < 2; ks++) {
            short8 bH = *(const short8*)&ah[(dt * 16 + c) * 64 + ks * 32 + hi * 8];
            short8 bL = *(const short8*)&al[(dt * 16 + c) * 64 + ks * 32 + hi * 8];
            oC[dt] = MFMA(pah[ks], bH, oC[dt]);
            oC[dt] = MFMA(pal[ks], bH, oC[dt]);
            oC[dt] = MFMA(pah[ks], bL, oC[dt]);
        }
    }
    float* ob = Og + ((size_t)bh * Ss + st * 64 + w * 16) * Dd;
#pragma unroll
    for (int dt = 0; dt < 4; dt++)
#pragma unroll
        for (int r = 0; r < 4; r++)
            ob[(hi * 4 + r) * 64 + dt * 16 + c] = oC[dt][r];
}

extern "C" void kernel_launch(void* const* d_in, const int* in_sizes, int n_in,
                              void* d_out, int out_size, void* d_ws, size_t ws_size,
                              hipStream_t stream) {
    const float* Q = (const float*)d_in[0];
    const float* K = (const float*)d_in[1];
    const float* V = (const float*)d_in[2];
    float* out = (float*)d_out;
    float* ws = (float*)d_ws;
    unsigned int* coef = (unsigned int*)d_ws;
    float* qlm  = ws + 16;
    float* klm  = qlm  + BH * Mm * Dd;
    float* smat = klm  + BH * Mm * Dd;
    float* atil = smat + BH * Mm * Mm;
    float* pnum = atil + BH * Mm * Mm;                    // [48][16][64][64]
    float* pden = pnum + (size_t)BH * NCH * Mm * Dd;      // [48][16][4][64]
    u16* ub   = (u16*)(pden + (size_t)BH * NCH * 4 * 64);
    u16* qlmh = ub;
    u16* qlml = qlmh + BH * Mm * Dd;
    u16* klmh = qlml + BH * Mm * Dd;
    u16* klml = klmh + BH * Mm * Dd;
    u16* abvh = klml + BH * Mm * Dd;
    u16* abvl = abvh + BH * Mm * Dd;

    hipMemsetAsync(d_ws, 0, 64, stream);   // coef maxes (all maxed values positive)

    k_landmarks<<<dim3(4, BH, 2), dim3(256), 0, stream>>>(Q, K, qlm, klm, qlmh, qlml, klmh, klml);
    k_lmsm<<<dim3(BH), dim3(256), 0, stream>>>(qlm, klm, smat, coef);
    k_pinv<<<dim3(BH), dim3(256), 12 * PLN * 2, stream>>>(smat, coef, atil);
    k_bvp<<<dim3(NCH, BH), dim3(256), 0, stream>>>(K, V, qlmh, qlml, pnum, pden);
    k_bvc<<<dim3(BH), dim3(256), 0, stream>>>(pnum, pden, atil, abvh, abvl);
    k_fout<<<dim3(Ss / 64, BH), dim3(256), 0, stream>>>(Q, klmh, klml, abvh, abvl, out);
}